// Round 13
// baseline (987.335 us; speedup 1.0000x reference)
//
#include <hip/hip_runtime.h>
#include <math.h>

#define B_  2
#define S_  1024
#define H_  4096
#define NH_ 32
#define HD_ 128
#define I_  11008
#define R_  2048   // B*S tokens

typedef __attribute__((ext_vector_type(4))) int i32x4;
typedef __attribute__((ext_vector_type(4))) float f32x4;
typedef __attribute__((ext_vector_type(8))) short bf16x8;

// Tiled int8 layout (v1, validated): for matrix [Rows][K], nk = K/64;
// tile (rb, kt) is 8192 B at ((rb*nk + kt)<<13), internally
// [kgrp 0..3][row 0..127][16B]  (kgrp = (k%64)/16).

struct PackJob {
    const int* W;            // int32 weight [N][K]
    signed char* out;        // tiled-i8 output
    int nk;                  // K/64
    int nt;                  // total tiles = nk * (N/128)
};

// ---------------------------------------------------------------------------
// global->LDS DMA. r7 LESSON: the GLOBAL src address is PER-LANE (must include
// lane*16); the LDS dest is wave-uniform, HW adds lane*16.
__device__ __forceinline__ void gload_lds16(const void* g, void* l) {
    __builtin_amdgcn_global_load_lds(
        (const __attribute__((address_space(1))) unsigned int*)g,
        (__attribute__((address_space(3))) unsigned int*)l, 16, 0, 0);
}

__device__ __forceinline__ unsigned short f2bf(float f) {
    unsigned int u = __float_as_uint(f);
    u += 0x7fffu + ((u >> 16) & 1u);   // RNE
    return (unsigned short)(u >> 16);
}

// pack one 8KB tile t (== (cb*nk + kt)) of job j. Math identical to the
// r5-validated packW_k.
__device__ __forceinline__ void pack_tile(const PackJob& j, int t, int tid) {
    const int nk = j.nk, K = nk << 6;
    const int kt = t % nk, cb = t / nk;
    int* otile = (int*)(j.out + ((long)t << 13));
#pragma unroll
    for (int i = 0; i < 8; ++i) {
        const int o = i * 256 + tid;
        const int g = o >> 9, r = (o >> 2) & 127, jj = o & 3;
        const int4 w4 = *(const int4*)(j.W + (long)(cb * 128 + r) * K
                                           + (long)kt * 64 + g * 16 + jj * 4);
        otile[o] = (w4.x & 255) | ((w4.y & 255) << 8) | ((w4.z & 255) << 16) | (w4.w << 24);
    }
}

// TAIL pack: runs AFTER a block's compute epilogue. pb = block's original id,
// np = grid size. No occupancy displacement, no sync interaction.
__device__ __forceinline__ void pack_tail(const PackJob& j1, const PackJob& j2,
                                          const PackJob& j3, int pb, int np, int tid) {
    const int tot = j1.nt + j2.nt + j3.nt;
    for (int t = pb; t < tot; t += np) {
        int lt = t;
        if (lt < j1.nt) { pack_tile(j1, lt, tid); continue; }
        lt -= j1.nt;
        if (lt < j2.nt) { pack_tile(j2, lt, tid); continue; }
        pack_tile(j3, lt - j2.nt, tid);
    }
}

// ---------------------------------------------------------------------------
// RMSNorm + int8 quant -> tiled-i8 (nk=64); tail-packs up to 3 weights.
__global__ __launch_bounds__(256)
void rmsnorm_quant_k(const float* __restrict__ x, const float* __restrict__ w,
                     signed char* __restrict__ out,
                     PackJob p1, PackJob p2, PackJob p3)
{
    const int tid = threadIdx.x;
    {
        __shared__ float red[4];
        const long row = blockIdx.x;
        const float4* xr = (const float4*)(x + row * H_);
        float4 xv[4];
        float ss = 0.f;
#pragma unroll
        for (int i = 0; i < 4; ++i) {
            xv[i] = xr[tid + i * 256];
            ss += xv[i].x * xv[i].x + xv[i].y * xv[i].y
                + xv[i].z * xv[i].z + xv[i].w * xv[i].w;
        }
#pragma unroll
        for (int off = 32; off; off >>= 1) ss += __shfl_xor(ss, off);
        if ((tid & 63) == 0) red[tid >> 6] = ss;
        __syncthreads();
        const float tot = red[0] + red[1] + red[2] + red[3];
        const float sc = 1.f / sqrtf(tot * (1.f / (float)H_) + 1e-6f);
        const float4* wr = (const float4*)w;
        int* ob = (int*)out;
        const long rb = row >> 7;
        const int rr = (int)(row & 127);
#pragma unroll
        for (int i = 0; i < 4; ++i) {
            const float4 wv = wr[tid + i * 256];
            const int b0 = (int)fminf(fmaxf(rintf(xv[i].x * sc * wv.x), -128.f), 127.f);
            const int b1 = (int)fminf(fmaxf(rintf(xv[i].y * sc * wv.y), -128.f), 127.f);
            const int b2 = (int)fminf(fmaxf(rintf(xv[i].z * sc * wv.z), -128.f), 127.f);
            const int b3 = (int)fminf(fmaxf(rintf(xv[i].w * sc * wv.w), -128.f), 127.f);
            const int packed = (b0 & 255) | ((b1 & 255) << 8) | ((b2 & 255) << 16) | (b3 << 24);
            const int j4 = tid + i * 256;          // int32 group within row
            const long a32 = ((rb * 64 + (j4 >> 4)) << 11) + (((j4 >> 2) & 3) << 9)
                           + (rr << 2) + (j4 & 3);
            ob[a32] = packed;
        }
    }
    pack_tail(p1, p2, p3, blockIdx.x, gridDim.x, tid);
}

// ---------------------------------------------------------------------------
// int8 GEMM (round-8 validated): BK=128 double-step, depth-2 ring, counted
// vmcnt(8), 64KB LDS -> 2 blocks/CU. Wave-out 64x64 (acc[4][4]).
// Optional tail-pack job after the epilogue.
__global__ __launch_bounds__(256, 2)
void gemm_i8t(const signed char* __restrict__ A8, const signed char* __restrict__ W8,
              const float* __restrict__ scale_ptr, const float* __restrict__ bias,
              const float* __restrict__ residual, float* __restrict__ C,
              const int N, const int K, const int gx, PackJob pj)
{
    __shared__ __align__(16) signed char lsA[2][16384];
    __shared__ __align__(16) signed char lsB[2][16384];

    const int pb0 = blockIdx.x;
    int bid = blockIdx.x;
    {   // bijective XCD chunked remap (m204)
        const int nwg = gridDim.x;
        const int q = nwg >> 3, r = nwg & 7;
        const int xcd = bid & 7, idx = bid >> 3;
        bid = (xcd < r) ? (xcd * (q + 1) + idx)
                        : (r * (q + 1) + (xcd - r) * q + idx);
    }
    const int bx = bid % gx, by = bid / gx;

    const int tid  = threadIdx.x;
    const int lane = tid & 63, wid = tid >> 6;
    const int bm = bx << 7, bn = by << 7;
    const int wm = (wid >> 1) << 6, wn = (wid & 1) << 6;

    i32x4 acc[4][4];
#pragma unroll
    for (int m = 0; m < 4; ++m)
#pragma unroll
        for (int n = 0; n < 4; ++n) acc[m][n] = (i32x4){0, 0, 0, 0};

    const int nk  = K >> 6;
    const int nk2 = K >> 7;
    const signed char* abase = A8 + ((long)bx * nk << 13);
    const signed char* bbase = W8 + ((long)by * nk << 13);
    const int sgg = wid * 4096 + lane * 16;        // GLOBAL src: per-lane
    const int sgl = wid * 4096;                    // LDS dest: wave-uniform

#pragma unroll
    for (int c = 0; c < 4; ++c) {
        gload_lds16(abase + sgg + c * 1024, lsA[0] + sgl + c * 1024);
        gload_lds16(bbase + sgg + c * 1024, lsB[0] + sgl + c * 1024);
    }

    for (int kt = 0; kt < nk2; ++kt) {
        const int cur = kt & 1, nxt = cur ^ 1;
        if (kt + 1 < nk2) {
            const signed char* at = abase + ((long)(kt + 1) << 14);
            const signed char* bt = bbase + ((long)(kt + 1) << 14);
#pragma unroll
            for (int c = 0; c < 4; ++c) {
                gload_lds16(at + sgg + c * 1024, lsA[nxt] + sgl + c * 1024);
                gload_lds16(bt + sgg + c * 1024, lsB[nxt] + sgl + c * 1024);
            }
            asm volatile("s_waitcnt vmcnt(8)" ::: "memory");
        } else {
            asm volatile("s_waitcnt vmcnt(0)" ::: "memory");
        }
        __builtin_amdgcn_s_barrier();

        const int kg = (lane >> 4) * 2048, fr = (lane & 15) * 16;
#pragma unroll
        for (int s = 0; s < 2; ++s) {
            const int off = s * 8192;
            i32x4 af[4], bf[4];
#pragma unroll
            for (int m = 0; m < 4; ++m)
                af[m] = *(const i32x4*)(lsA[cur] + off + kg + wm * 16 + m * 256 + fr);
#pragma unroll
            for (int n = 0; n < 4; ++n)
                bf[n] = *(const i32x4*)(lsB[cur] + off + kg + wn * 16 + n * 256 + fr);
            __builtin_amdgcn_s_setprio(1);
#pragma unroll
            for (int m = 0; m < 4; ++m)
#pragma unroll
                for (int n = 0; n < 4; ++n)
                    acc[m][n] = __builtin_amdgcn_mfma_i32_16x16x64_i8(af[m], bf[n], acc[m][n], 0, 0, 0);
            __builtin_amdgcn_s_setprio(0);
        }
        __builtin_amdgcn_s_barrier();
    }

    const float s = *scale_ptr;
    const int rq = (lane >> 4) * 4, fc = lane & 15;
#pragma unroll
    for (int m = 0; m < 4; ++m) {
#pragma unroll
        for (int n = 0; n < 4; ++n) {
            const int col = bn + wn + n * 16 + fc;
            const float bcol = bias[col];
#pragma unroll
            for (int r = 0; r < 4; ++r) {
                const int row = bm + wm + m * 16 + rq + r;
                float v = (float)acc[m][n][r] * s + bcol;
                if (residual) v += residual[(long)row * N + col];
                C[(long)row * N + col] = v;
            }
        }
    }
    const PackJob J0{nullptr, nullptr, 0, 0};
    pack_tail(pj, J0, J0, pb0, gridDim.x, tid);
}

// ---------------------------------------------------------------------------
// Fused gate+up int8 GEMM (r11 validated, clean — no pack duty).
__global__ __launch_bounds__(256, 2)
void gemm_gu(const signed char* __restrict__ A8, const signed char* __restrict__ G8,
             const signed char* __restrict__ U8,
             const float* __restrict__ sg_p, const float* __restrict__ bg,
             const float* __restrict__ su_p, const float* __restrict__ bu,
             const float* __restrict__ qscale, signed char* __restrict__ out8,
             const int N, const int K, const int gx)
{
    __shared__ __align__(16) signed char lsA[2][8192];
    __shared__ __align__(16) signed char lsG[2][8192];
    __shared__ __align__(16) signed char lsU[2][8192];

    int bid = blockIdx.x;
    {   // bijective XCD chunked remap
        const int nwg = gridDim.x;
        const int q = nwg >> 3, r = nwg & 7;
        const int xcd = bid & 7, idx = bid >> 3;
        bid = (xcd < r) ? (xcd * (q + 1) + idx)
                        : (r * (q + 1) + (xcd - r) * q + idx);
    }
    const int bx = bid % gx, by = bid / gx;
    const int tid = threadIdx.x, lane = tid & 63, wid = tid >> 6;
    const int bm = bx << 7, bn = by << 7;
    const int wm = (wid >> 1) << 6, wn = (wid & 1) << 6;

    i32x4 ag[4][4], au[4][4];
#pragma unroll
    for (int m = 0; m < 4; ++m)
#pragma unroll
        for (int n = 0; n < 4; ++n) {
            ag[m][n] = (i32x4){0, 0, 0, 0};
            au[m][n] = (i32x4){0, 0, 0, 0};
        }

    const int nk = K >> 6;
    const signed char* abase = A8 + ((long)bx * nk << 13);
    const signed char* gbase = G8 + ((long)by * nk << 13);
    const signed char* ubase = U8 + ((long)by * nk << 13);
    const int sgg = wid * 2048 + lane * 16;        // GLOBAL src: per-lane
    const int sgl = wid * 2048;                    // LDS dest: wave-uniform

#pragma unroll
    for (int c = 0; c < 2; ++c) {
        gload_lds16(abase + sgg + c * 1024, lsA[0] + sgl + c * 1024);
        gload_lds16(gbase + sgg + c * 1024, lsG[0] + sgl + c * 1024);
        gload_lds16(ubase + sgg + c * 1024, lsU[0] + sgl + c * 1024);
    }

    for (int kt = 0; kt < nk; ++kt) {
        const int cur = kt & 1, nxt = cur ^ 1;
        if (kt + 1 < nk) {
            const signed char* at = abase + ((long)(kt + 1) << 13);
            const signed char* gt = gbase + ((long)(kt + 1) << 13);
            const signed char* ut = ubase + ((long)(kt + 1) << 13);
#pragma unroll
            for (int c = 0; c < 2; ++c) {
                gload_lds16(at + sgg + c * 1024, lsA[nxt] + sgl + c * 1024);
                gload_lds16(gt + sgg + c * 1024, lsG[nxt] + sgl + c * 1024);
                gload_lds16(ut + sgg + c * 1024, lsU[nxt] + sgl + c * 1024);
            }
            asm volatile("s_waitcnt vmcnt(6)" ::: "memory");   // drain step kt's 6
        } else {
            asm volatile("s_waitcnt vmcnt(0)" ::: "memory");
        }
        __builtin_amdgcn_s_barrier();              // step kt visible

        const int kg = (lane >> 4) * 2048, fr = (lane & 15) * 16;
        i32x4 af[4], gf[4], uf[4];
#pragma unroll
        for (int m = 0; m < 4; ++m)
            af[m] = *(const i32x4*)(lsA[cur] + kg + wm * 16 + m * 256 + fr);
#pragma unroll
        for (int n = 0; n < 4; ++n) {
            gf[n] = *(const i32x4*)(lsG[cur] + kg + wn * 16 + n * 256 + fr);
            uf[n] = *(const i32x4*)(lsU[cur] + kg + wn * 16 + n * 256 + fr);
        }
        __builtin_amdgcn_s_setprio(1);
#pragma unroll
        for (int m = 0; m < 4; ++m)
#pragma unroll
            for (int n = 0; n < 4; ++n) {
                ag[m][n] = __builtin_amdgcn_mfma_i32_16x16x64_i8(af[m], gf[n], ag[m][n], 0, 0, 0);
                au[m][n] = __builtin_amdgcn_mfma_i32_16x16x64_i8(af[m], uf[n], au[m][n], 0, 0, 0);
            }
        __builtin_amdgcn_s_setprio(0);
        __builtin_amdgcn_s_barrier();              // buf[cur] free
    }

    const float sg = *sg_p, su = *su_p;
    const float dinv = 1.f / qscale[0];
    const int nko = N >> 6;
    const int rq = (lane >> 4) * 4, fc = lane & 15;
#pragma unroll
    for (int m = 0; m < 4; ++m) {
#pragma unroll
        for (int n = 0; n < 4; ++n) {
            const int col = bn + wn + n * 16 + fc;
            const float bgc = bg[col], buc = bu[col];
            const int ktc = col >> 6, kgc = (col >> 4) & 3, jc = col & 15;
#pragma unroll
            for (int r = 0; r < 4; ++r) {
                const int row = bm + wm + m * 16 + rq + r;
                const float g = (float)ag[m][n][r] * sg + bgc;
                const float u = (float)au[m][n][r] * su + buc;
                const float a = g / (1.f + __expf(-g)) * u;
                const float qv = fminf(fmaxf(rintf(a * dinv), -128.f), 127.f);
                const long addr = (((long)(row >> 7) * nko + ktc) << 13)
                                + (kgc << 11) + ((row & 127) << 4) + jc;
                out8[addr] = (signed char)(int)qv;
            }
        }
    }
}

// ---------------------------------------------------------------------------
// RoPE applied in-place to q and k, layout [B,S,NH,HD] == [B,S,H] h-major.
__global__ __launch_bounds__(256)
void rope_k(float* __restrict__ q, float* __restrict__ k)
{
    const int row = blockIdx.x;            // token index b*S+s
    const int s = row & (S_ - 1);
    float* qr = q + (long)row * H_;
    float* kr = k + (long)row * H_;
    for (int t = threadIdx.x; t < NH_ * 64; t += 256) {
        const int nh = t >> 6, i = t & 63;
        const float inv = powf(10000.f, -(float)(2 * i) * (1.f / 128.f));
        const float f = (float)s * inv;
        float sn, c;
        sincosf(f, &sn, &c);
        const int base = nh * 128 + i;
        const float q0 = qr[base], q1 = qr[base + 64];
        qr[base]      = q0 * c - q1 * sn;
        qr[base + 64] = q1 * c + q0 * sn;
        const float k0 = kr[base], k1 = kr[base + 64];
        kr[base]      = k0 * c - k1 * sn;
        kr[base + 64] = k1 * c + k0 * sn;
    }
}

// ---------------------------------------------------------------------------
// Flash attention (r8 validated); epilogue fuses o-quant -> tiled-i8;
// tail-packs two weights (Wg, Wu) after the epilogue.
__global__ __launch_bounds__(256, 3)
void attn_mfma_k(const float* __restrict__ q, const float* __restrict__ k,
                 const float* __restrict__ v, signed char* __restrict__ out8,
                 const float* __restrict__ osc, PackJob p1, PackJob p2)
{
    __shared__ __align__(16) char lsK[8192];        // [32 krow][128 d] bf16, XOR swizzle
    __shared__ __align__(16) char lsV[10240];       // V^T [128 d][40 pitch] bf16
    __shared__ __align__(16) char lsP[4][1024];     // per-wave P [16][32] bf16, XOR swizzle

    const int tid = threadIdx.x, lane = tid & 63, wid = tid >> 6;
    const int bid = blockIdx.x;
    const int qt = 15 - (bid >> 6);                 // reversed: long blocks first
    const int bh = bid & 63;
    const int b = bh >> 5, h = bh & 31;
    const int q0 = qt * 64;
    const int qw = q0 + wid * 16;                   // this wave's first q row

    const float* qbase = q + (long)(b * S_) * H_ + (long)h * HD_;
    const float* kbase = k + (long)(b * S_) * H_ + (long)h * HD_;
    const float* vbase = v + (long)(b * S_) * H_ + (long)h * HD_;

    const int frow = lane & 15, fgrp = lane >> 4;
    const float sc = 0.08838834764831845f;          // 1/sqrt(128), folded into Q

    bf16x8 qf[4];
    {
        const float* qr = qbase + (long)(qw + frow) * H_;
#pragma unroll
        for (int c = 0; c < 4; ++c) {
            const float4 a = *(const float4*)(qr + c * 32 + fgrp * 8);
            const float4 bq = *(const float4*)(qr + c * 32 + fgrp * 8 + 4);
            bf16x8 t;
            t[0] = (short)f2bf(a.x * sc);  t[1] = (short)f2bf(a.y * sc);
            t[2] = (short)f2bf(a.z * sc);  t[3] = (short)f2bf(a.w * sc);
            t[4] = (short)f2bf(bq.x * sc); t[5] = (short)f2bf(bq.y * sc);
            t[6] = (short)f2bf(bq.z * sc); t[7] = (short)f2bf(bq.w * sc);
            qf[c] = t;
        }
    }

    f32x4 oacc[8];
#pragma unroll
    for (int n2 = 0; n2 < 8; ++n2) oacc[n2] = (f32x4){0.f, 0.f, 0.f, 0.f};
    float mr[4] = {-1e30f, -1e30f, -1e30f, -1e30f};
    float lr[4] = {0.f, 0.f, 0.f, 0.f};

    const int nt = (q0 >> 5) + 2;
    for (int kt = 0; kt < nt; ++kt) {
        if (kt) __syncthreads();
        {
            const float* kg = kbase + (long)(kt * 32) * H_;
            const float* vg = vbase + (long)(kt * 32) * H_;
#pragma unroll
            for (int i = 0; i < 4; ++i) {
                const int lin = i * 256 + tid;
                const int kr = lin >> 5;
                const int d4 = (lin & 31) * 4;
                const float4 kv = *(const float4*)(kg + (long)kr * H_ + d4);
                const float4 vv = *(const float4*)(vg + (long)kr * H_ + d4);
                ushort4 kb;
                kb.x = f2bf(kv.x); kb.y = f2bf(kv.y); kb.z = f2bf(kv.z); kb.w = f2bf(kv.w);
                *(ushort4*)(lsK + kr * 256 + ((d4 * 2) ^ ((kr & 7) << 4))) = kb;
                *(unsigned short*)(lsV + (d4 + 0) * 80 + kr * 2) = f2bf(vv.x);
                *(unsigned short*)(lsV + (d4 + 1) * 80 + kr * 2) = f2bf(vv.y);
                *(unsigned short*)(lsV + (d4 + 2) * 80 + kr * 2) = f2bf(vv.z);
                *(unsigned short*)(lsV + (d4 + 3) * 80 + kr * 2) = f2bf(vv.w);
            }
        }
        __syncthreads();

        if (kt * 32 <= qw + 15) {
            f32x4 s0 = (f32x4){0.f, 0.f, 0.f, 0.f};
            f32x4 s1 = (f32x4){0.f, 0.f, 0.f, 0.f};
            const int swz = (frow & 7) << 4;
#pragma unroll
            for (int c = 0; c < 4; ++c) {
                const int dby = c * 64 + fgrp * 16;
                const bf16x8 kfA = *(const bf16x8*)(lsK + frow * 256 + (dby ^ swz));
                const bf16x8 kfB = *(const bf16x8*)(lsK + (frow + 16) * 256 + (dby ^ swz));
                s0 = __builtin_amdgcn_mfma_f32_16x16x32_bf16(qf[c], kfA, s0, 0, 0, 0);
                s1 = __builtin_amdgcn_mfma_f32_16x16x32_bf16(qf[c], kfB, s1, 0, 0, 0);
            }

            const int colg0 = kt * 32 + frow;
            float cf[4];
#pragma unroll
            for (int r = 0; r < 4; ++r) {
                const int rowg = qw + fgrp * 4 + r;
                const float a0 = (colg0 <= rowg) ? s0[r] : -1e30f;
                const float a1 = (colg0 + 16 <= rowg) ? s1[r] : -1e30f;
                float mx = fmaxf(a0, a1);
#pragma unroll
                for (int off2 = 1; off2 < 16; off2 <<= 1) mx = fmaxf(mx, __shfl_xor(mx, off2));
                const float mnew = fmaxf(mr[r], mx);
                cf[r] = __expf(mr[r] - mnew);
                mr[r] = mnew;
                const float p0 = __expf(a0 - mnew);
                const float p1 = __expf(a1 - mnew);
                float sm = p0 + p1;
#pragma unroll
                for (int off2 = 1; off2 < 16; off2 <<= 1) sm += __shfl_xor(sm, off2);
                lr[r] = lr[r] * cf[r] + sm;
                const int row = fgrp * 4 + r;
                const int psw = (row & 3) << 4;
                *(unsigned short*)(lsP[wid] + row * 64 + ((frow * 2) ^ psw)) = f2bf(p0);
                *(unsigned short*)(lsP[wid] + row * 64 + (((16 + frow) * 2) ^ psw)) = f2bf(p1);
            }
#pragma unroll
            for (int n2 = 0; n2 < 8; ++n2) {
#pragma unroll
                for (int r = 0; r < 4; ++r) oacc[n2][r] *= cf[r];
            }
            const bf16x8 pf = *(const bf16x8*)(lsP[wid] + frow * 64 + ((fgrp * 16) ^ ((frow & 3) << 4)));
#pragma unroll
            for (int n2 = 0; n2 < 8; ++n2) {
                const bf16x8 vf = *(const bf16x8*)(lsV + (n2 * 16 + frow) * 80 + fgrp * 16);
                oacc[n2] = __builtin_amdgcn_mfma_f32_16x16x32_bf16(pf, vf, oacc[n2], 0, 0, 0);
            }
        }
    }

    // epilogue: o = oacc/l, q8 = clip(rint(o/osc)) -> tiled-i8 (nk = 64)
    const float oinv = 1.f / osc[0];
    float inv[4];
#pragma unroll
    for (int r = 0; r < 4; ++r) inv[r] = 1.f / lr[r];
#pragma unroll
    for (int n2 = 0; n2 < 8; ++n2) {
        const int kk = h * 128 + n2 * 16 + frow;
        const int ktc = kk >> 6, kgc = (kk >> 4) & 3, jc = kk & 15;
#pragma unroll
        for (int r = 0; r < 4; ++r) {
            const int rowt = b * S_ + qw + fgrp * 4 + r;
            const float ov = oacc[n2][r] * inv[r];
            const float qv = fminf(fmaxf(rintf(ov * oinv), -128.f), 127.f);
            const long addr = (((long)(rowt >> 7) * 64 + ktc) << 13)
                            + (kgc << 11) + ((rowt & 127) << 4) + jc;
            out8[addr] = (signed char)(int)qv;
        }
    }
    const PackJob J0{nullptr, nullptr, 0, 0};
    pack_tail(p1, p2, J0, blockIdx.x, gridDim.x, tid);
}

// ---------------------------------------------------------------------------
extern "C" void kernel_launch(void* const* d_in, const int* in_sizes, int n_in,
                              void* d_out, int out_size, void* d_ws, size_t ws_size,
                              hipStream_t stream)
{
    const float* hidden = (const float*)d_in[0];
    const float* ln1 = (const float*)d_in[1];
    const float* ln2 = (const float*)d_in[2];
    const int* Wq = (const int*)d_in[3];
    const int* Wk = (const int*)d_in[4];
    const int* Wv = (const int*)d_in[5];
    const int* Wo = (const int*)d_in[6];
    const int* Wg = (const int*)d_in[7];
    const int* Wu = (const int*)d_in[8];
    const int* Wd = (const int*)d_in[9];
    const float* bq = (const float*)d_in[10];
    const float* bk = (const float*)d_in[11];
    const float* bv = (const float*)d_in[12];
    const float* bo = (const float*)d_in[13];
    const float* bg = (const float*)d_in[14];
    const float* bu = (const float*)d_in[15];
    const float* bd = (const float*)d_in[16];
    const float* sq = (const float*)d_in[17];
    const float* sk = (const float*)d_in[18];
    const float* sv = (const float*)d_in[19];
    const float* so = (const float*)d_in[20];
    const float* sg = (const float*)d_in[21];
    const float* su = (const float*)d_in[22];
    const float* sd = (const float*)d_in[23];
    const float* o_sc = (const float*)d_in[24];
    const float* d_sc = (const float*)d_in[25];

    // workspace layout (MiB offsets, peak 233 MiB; 236 validated in r1):
    //  [0,8)     HQ8 tiled i8 (hq / oq / hq2, sequential reuse)
    //  [8,30)    AQ8 tiled i8 (2048 x 11008)
    //  [30,46)   WPq ; [46,62) WPk ; [62,78) WPv   (packed in rmsnorm1 tail)
    //  [78,94)   WPo                                (packed in gemmQ tail)
    //  [94,126)  Qb fp32 -> (post-attn) Hb
    //  [126,158) Kb ; [158,190) Vb                  (dead after attn)
    //  [190,233) WPg                                (packed in attn tail)
    //  [30,73)   WPu over dead WPq/k/v              (packed in attn tail)
    //  [126,169) WPd over dead Kb/Vb                (packed in rmsnorm2 tail)
    char* ws = (char*)d_ws;
    signed char* HQ8 = (signed char*)ws;
    signed char* AQ8 = (signed char*)(ws + ((size_t)8 << 20));
    signed char* WPq = (signed char*)(ws + ((size_t)30 << 20));
    signed char* WPk = (signed char*)(ws + ((size_t)46 << 20));
    signed char* WPv = (signed char*)(ws + ((size_t)62 << 20));
    signed char* WPo = (signed char*)(ws + ((size_t)78 << 20));
    float* Qb = (float*)(ws + ((size_t)94 << 20));
    float* Kb = (float*)(ws + ((size_t)126 << 20));
    float* Vb = (float*)(ws + ((size_t)158 << 20));
    signed char* WPg = (signed char*)(ws + ((size_t)190 << 20));
    signed char* WPu = (signed char*)(ws + ((size_t)30 << 20));
    signed char* WPd = (signed char*)(ws + ((size_t)126 << 20));
    float* Hb = Qb;
    float* out = (float*)d_out;

    const dim3 blk(256);
    const int gxH = R_ / 128;                 // 16 row blocks
    const int nwgH = gxH * (H_ / 128);        // 512
    const int nwgI = gxH * (I_ / 128);        // 1376
    const int ntH = (H_ / 64) * (H_ / 128);   // 2048 tiles (H-weight)
    const int ntI = (H_ / 64) * (I_ / 128);   // 5504 tiles (Wg/Wu)
    const int ntD = (I_ / 64) * (H_ / 128);   // 5504 tiles (Wd)
    const PackJob JQ{Wq, WPq, H_ / 64, ntH};
    const PackJob JK{Wk, WPk, H_ / 64, ntH};
    const PackJob JV{Wv, WPv, H_ / 64, ntH};
    const PackJob JO{Wo, WPo, H_ / 64, ntH};
    const PackJob JG{Wg, WPg, H_ / 64, ntI};
    const PackJob JU{Wu, WPu, H_ / 64, ntI};
    const PackJob JD{Wd, WPd, I_ / 64, ntD};
    const PackJob J0{nullptr, nullptr, 0, 0};

    // 1: rmsnorm1 + tail-pack {Wq, Wk, Wv}  (3 tiles/block over 2048 blocks)
    rmsnorm_quant_k<<<R_, blk, 0, stream>>>(hidden, ln1, HQ8, JQ, JK, JV);
    // 2: Q projection + tail-pack Wo
    gemm_i8t<<<nwgH, blk, 0, stream>>>(HQ8, WPq, sq, bq, nullptr, Qb, H_, H_, gxH, JO);
    // 3-4: K, V projections
    gemm_i8t<<<nwgH, blk, 0, stream>>>(HQ8, WPk, sk, bk, nullptr, Kb, H_, H_, gxH, J0);
    gemm_i8t<<<nwgH, blk, 0, stream>>>(HQ8, WPv, sv, bv, nullptr, Vb, H_, H_, gxH, J0);
    // 5: rope
    rope_k<<<R_, blk, 0, stream>>>(Qb, Kb);
    // 6: attention + tail-pack {Wg, Wu}  (10.75 tiles/block over 1024 blocks)
    attn_mfma_k<<<B_ * NH_ * (S_ / 64), blk, 0, stream>>>(Qb, Kb, Vb, HQ8, o_sc, JG, JU);
    // 7: o projection (+residual)
    gemm_i8t<<<nwgH, blk, 0, stream>>>(HQ8, WPo, so, bo, hidden, Hb, H_, H_, gxH, J0);
    // 8: rmsnorm2 + tail-pack Wd  (2.7 tiles/block over 2048 blocks)
    rmsnorm_quant_k<<<R_, blk, 0, stream>>>(Hb, ln2, HQ8, JD, J0, J0);
    // 9: fused gate+up GEMM (clean)
    gemm_gu<<<nwgI, blk, 0, stream>>>(HQ8, WPg, WPu, sg, bg, su, bu,
                                      d_sc, AQ8, I_, H_, gxH);
    // 10: down projection (+residual) -> out
    gemm_i8t<<<nwgH, blk, 0, stream>>>(AQ8, WPd, sd, bd, Hb, out, H_, I_, gxH, J0);
}

// Round 15
// 940.172 us; speedup vs baseline: 1.0502x; 1.0502x over previous
//
#include <hip/hip_runtime.h>
#include <math.h>

#define B_  2
#define S_  1024
#define H_  4096
#define NH_ 32
#define HD_ 128
#define I_  11008
#define R_  2048   // B*S tokens

typedef __attribute__((ext_vector_type(4))) int i32x4;
typedef __attribute__((ext_vector_type(4))) float f32x4;
typedef __attribute__((ext_vector_type(8))) short bf16x8;

// Tiled int8 layout (v1, validated): for matrix [Rows][K], nk = K/64;
// tile (rb, kt) is 8192 B at ((rb*nk + kt)<<13), internally
// [kgrp 0..3][row 0..127][16B]  (kgrp = (k%64)/16).
//
// r14 LESSON: kernels with hand-counted s_waitcnt vmcnt(N) must never spill —
// scratch buffer ops count toward vmcnt and silently break the count. Keep
// launch_bounds at the no-spill occupancy (gemm_gu: (256,2), 96+128 regs).

// ---------------------------------------------------------------------------
// global->LDS DMA. r7 LESSON: the GLOBAL src address is PER-LANE (must include
// lane*16); the LDS dest is wave-uniform, HW adds lane*16.
__device__ __forceinline__ void gload_lds16(const void* g, void* l) {
    __builtin_amdgcn_global_load_lds(
        (const __attribute__((address_space(1))) unsigned int*)g,
        (__attribute__((address_space(3))) unsigned int*)l, 16, 0, 0);
}

__device__ __forceinline__ unsigned short f2bf(float f) {
    unsigned int u = __float_as_uint(f);
    u += 0x7fffu + ((u >> 16) & 1u);   // RNE
    return (unsigned short)(u >> 16);
}

// ---------------------------------------------------------------------------
// Pack one W (int32 [N][K]) into tiled-i8. Grid: (K/64, N/128).
__global__ __launch_bounds__(256)
void packW_k(const int* __restrict__ W, signed char* __restrict__ out, const int K)
{
    const int kt = blockIdx.x, cb = blockIdx.y, nk = gridDim.x;
    const int t = threadIdx.x;
    int* otile = (int*)(out + ((long)(cb * nk + kt) << 13));
#pragma unroll
    for (int i = 0; i < 8; ++i) {
        const int o = i * 256 + t;                 // int32 index in tile
        const int g = o >> 9, r = (o >> 2) & 127, jj = o & 3;
        const int4 w4 = *(const int4*)(W + (long)(cb * 128 + r) * K + kt * 64 + g * 16 + jj * 4);
        otile[o] = (w4.x & 255) | ((w4.y & 255) << 8) | ((w4.z & 255) << 16) | (w4.w << 24);
    }
}

// ---------------------------------------------------------------------------
// RMSNorm + int8 quant (scale folded into w). Output in tiled-i8 (nk=64).
__global__ __launch_bounds__(256)
void rmsnorm_quant_k(const float* __restrict__ x, const float* __restrict__ w,
                     signed char* __restrict__ out)
{
    __shared__ float red[4];
    const int tid = threadIdx.x;
    const long row = blockIdx.x;
    const float4* xr = (const float4*)(x + row * H_);
    float4 xv[4];
    float ss = 0.f;
#pragma unroll
    for (int i = 0; i < 4; ++i) {
        xv[i] = xr[tid + i * 256];
        ss += xv[i].x * xv[i].x + xv[i].y * xv[i].y
            + xv[i].z * xv[i].z + xv[i].w * xv[i].w;
    }
#pragma unroll
    for (int off = 32; off; off >>= 1) ss += __shfl_xor(ss, off);
    if ((tid & 63) == 0) red[tid >> 6] = ss;
    __syncthreads();
    const float tot = red[0] + red[1] + red[2] + red[3];
    const float sc = 1.f / sqrtf(tot * (1.f / (float)H_) + 1e-6f);
    const float4* wr = (const float4*)w;
    int* ob = (int*)out;
    const long rb = row >> 7;
    const int rr = (int)(row & 127);
#pragma unroll
    for (int i = 0; i < 4; ++i) {
        const float4 wv = wr[tid + i * 256];
        const int b0 = (int)fminf(fmaxf(rintf(xv[i].x * sc * wv.x), -128.f), 127.f);
        const int b1 = (int)fminf(fmaxf(rintf(xv[i].y * sc * wv.y), -128.f), 127.f);
        const int b2 = (int)fminf(fmaxf(rintf(xv[i].z * sc * wv.z), -128.f), 127.f);
        const int b3 = (int)fminf(fmaxf(rintf(xv[i].w * sc * wv.w), -128.f), 127.f);
        const int packed = (b0 & 255) | ((b1 & 255) << 8) | ((b2 & 255) << 16) | (b3 << 24);
        const int j4 = tid + i * 256;              // int32 group within row
        const long a32 = ((rb * 64 + (j4 >> 4)) << 11) + (((j4 >> 2) & 3) << 9)
                       + (rr << 2) + (j4 & 3);
        ob[a32] = packed;
    }
}

// ---------------------------------------------------------------------------
// int8 GEMM (round-8 validated): BK=128 double-step, depth-2 ring, counted
// vmcnt(8), 64KB LDS -> 2 blocks/CU. Wave-out 64x64 (acc[4][4]).
__global__ __launch_bounds__(256, 2)
void gemm_i8t(const signed char* __restrict__ A8, const signed char* __restrict__ W8,
              const float* __restrict__ scale_ptr, const float* __restrict__ bias,
              const float* __restrict__ residual, float* __restrict__ C,
              const int N, const int K, const int gx)
{
    __shared__ __align__(16) signed char lsA[2][16384];
    __shared__ __align__(16) signed char lsB[2][16384];

    int bid = blockIdx.x;
    {   // bijective XCD chunked remap (m204)
        const int nwg = gridDim.x;
        const int q = nwg >> 3, r = nwg & 7;
        const int xcd = bid & 7, idx = bid >> 3;
        bid = (xcd < r) ? (xcd * (q + 1) + idx)
                        : (r * (q + 1) + (xcd - r) * q + idx);
    }
    const int bx = bid % gx, by = bid / gx;

    const int tid  = threadIdx.x;
    const int lane = tid & 63, wid = tid >> 6;
    const int bm = bx << 7, bn = by << 7;
    const int wm = (wid >> 1) << 6, wn = (wid & 1) << 6;

    i32x4 acc[4][4];
#pragma unroll
    for (int m = 0; m < 4; ++m)
#pragma unroll
        for (int n = 0; n < 4; ++n) acc[m][n] = (i32x4){0, 0, 0, 0};

    const int nk  = K >> 6;
    const int nk2 = K >> 7;
    const signed char* abase = A8 + ((long)bx * nk << 13);
    const signed char* bbase = W8 + ((long)by * nk << 13);
    const int sgg = wid * 4096 + lane * 16;        // GLOBAL src: per-lane
    const int sgl = wid * 4096;                    // LDS dest: wave-uniform

#pragma unroll
    for (int c = 0; c < 4; ++c) {
        gload_lds16(abase + sgg + c * 1024, lsA[0] + sgl + c * 1024);
        gload_lds16(bbase + sgg + c * 1024, lsB[0] + sgl + c * 1024);
    }

    for (int kt = 0; kt < nk2; ++kt) {
        const int cur = kt & 1, nxt = cur ^ 1;
        if (kt + 1 < nk2) {
            const signed char* at = abase + ((long)(kt + 1) << 14);
            const signed char* bt = bbase + ((long)(kt + 1) << 14);
#pragma unroll
            for (int c = 0; c < 4; ++c) {
                gload_lds16(at + sgg + c * 1024, lsA[nxt] + sgl + c * 1024);
                gload_lds16(bt + sgg + c * 1024, lsB[nxt] + sgl + c * 1024);
            }
            asm volatile("s_waitcnt vmcnt(8)" ::: "memory");
        } else {
            asm volatile("s_waitcnt vmcnt(0)" ::: "memory");
        }
        __builtin_amdgcn_s_barrier();

        const int kg = (lane >> 4) * 2048, fr = (lane & 15) * 16;
#pragma unroll
        for (int s = 0; s < 2; ++s) {
            const int off = s * 8192;
            i32x4 af[4], bf[4];
#pragma unroll
            for (int m = 0; m < 4; ++m)
                af[m] = *(const i32x4*)(lsA[cur] + off + kg + wm * 16 + m * 256 + fr);
#pragma unroll
            for (int n = 0; n < 4; ++n)
                bf[n] = *(const i32x4*)(lsB[cur] + off + kg + wn * 16 + n * 256 + fr);
            __builtin_amdgcn_s_setprio(1);
#pragma unroll
            for (int m = 0; m < 4; ++m)
#pragma unroll
                for (int n = 0; n < 4; ++n)
                    acc[m][n] = __builtin_amdgcn_mfma_i32_16x16x64_i8(af[m], bf[n], acc[m][n], 0, 0, 0);
            __builtin_amdgcn_s_setprio(0);
        }
        __builtin_amdgcn_s_barrier();
    }

    const float s = *scale_ptr;
    const int rq = (lane >> 4) * 4, fc = lane & 15;
#pragma unroll
    for (int m = 0; m < 4; ++m) {
#pragma unroll
        for (int n = 0; n < 4; ++n) {
            const int col = bn + wn + n * 16 + fc;
            const float bcol = bias[col];
#pragma unroll
            for (int r = 0; r < 4; ++r) {
                const int row = bm + wm + m * 16 + rq + r;
                float v = (float)acc[m][n][r] * s + bcol;
                if (residual) v += residual[(long)row * N + col];
                C[(long)row * N + col] = v;
            }
        }
    }
}

// ---------------------------------------------------------------------------
// Fused gate+up int8 GEMM (r11 validated): one block computes both g and u
// 128x128 tiles over the SAME staged A-tile, then silu(g)*u -> quant -> AQ8.
// Sync: issue 6 gloads -> vmcnt(6) -> barrier -> frag reads + 32 MFMA ->
// barrier. 48KB LDS, (256,2) — do NOT raise: spill breaks counted vmcnt (r14).
__global__ __launch_bounds__(256, 2)
void gemm_gu(const signed char* __restrict__ A8, const signed char* __restrict__ G8,
             const signed char* __restrict__ U8,
             const float* __restrict__ sg_p, const float* __restrict__ bg,
             const float* __restrict__ su_p, const float* __restrict__ bu,
             const float* __restrict__ qscale, signed char* __restrict__ out8,
             const int N, const int K, const int gx)
{
    __shared__ __align__(16) signed char lsA[2][8192];
    __shared__ __align__(16) signed char lsG[2][8192];
    __shared__ __align__(16) signed char lsU[2][8192];

    int bid = blockIdx.x;
    {   // bijective XCD chunked remap
        const int nwg = gridDim.x;
        const int q = nwg >> 3, r = nwg & 7;
        const int xcd = bid & 7, idx = bid >> 3;
        bid = (xcd < r) ? (xcd * (q + 1) + idx)
                        : (r * (q + 1) + (xcd - r) * q + idx);
    }
    const int bx = bid % gx, by = bid / gx;
    const int tid = threadIdx.x, lane = tid & 63, wid = tid >> 6;
    const int bm = bx << 7, bn = by << 7;
    const int wm = (wid >> 1) << 6, wn = (wid & 1) << 6;

    i32x4 ag[4][4], au[4][4];
#pragma unroll
    for (int m = 0; m < 4; ++m)
#pragma unroll
        for (int n = 0; n < 4; ++n) {
            ag[m][n] = (i32x4){0, 0, 0, 0};
            au[m][n] = (i32x4){0, 0, 0, 0};
        }

    const int nk = K >> 6;
    const signed char* abase = A8 + ((long)bx * nk << 13);
    const signed char* gbase = G8 + ((long)by * nk << 13);
    const signed char* ubase = U8 + ((long)by * nk << 13);
    const int sgg = wid * 2048 + lane * 16;        // GLOBAL src: per-lane
    const int sgl = wid * 2048;                    // LDS dest: wave-uniform

#pragma unroll
    for (int c = 0; c < 2; ++c) {
        gload_lds16(abase + sgg + c * 1024, lsA[0] + sgl + c * 1024);
        gload_lds16(gbase + sgg + c * 1024, lsG[0] + sgl + c * 1024);
        gload_lds16(ubase + sgg + c * 1024, lsU[0] + sgl + c * 1024);
    }

    for (int kt = 0; kt < nk; ++kt) {
        const int cur = kt & 1, nxt = cur ^ 1;
        if (kt + 1 < nk) {
            const signed char* at = abase + ((long)(kt + 1) << 13);
            const signed char* gt = gbase + ((long)(kt + 1) << 13);
            const signed char* ut = ubase + ((long)(kt + 1) << 13);
#pragma unroll
            for (int c = 0; c < 2; ++c) {
                gload_lds16(at + sgg + c * 1024, lsA[nxt] + sgl + c * 1024);
                gload_lds16(gt + sgg + c * 1024, lsG[nxt] + sgl + c * 1024);
                gload_lds16(ut + sgg + c * 1024, lsU[nxt] + sgl + c * 1024);
            }
            asm volatile("s_waitcnt vmcnt(6)" ::: "memory");   // drain step kt's 6
        } else {
            asm volatile("s_waitcnt vmcnt(0)" ::: "memory");
        }
        __builtin_amdgcn_s_barrier();              // step kt visible

        const int kg = (lane >> 4) * 2048, fr = (lane & 15) * 16;
        i32x4 af[4], gf[4], uf[4];
#pragma unroll
        for (int m = 0; m < 4; ++m)
            af[m] = *(const i32x4*)(lsA[cur] + kg + wm * 16 + m * 256 + fr);
#pragma unroll
        for (int n = 0; n < 4; ++n) {
            gf[n] = *(const i32x4*)(lsG[cur] + kg + wn * 16 + n * 256 + fr);
            uf[n] = *(const i32x4*)(lsU[cur] + kg + wn * 16 + n * 256 + fr);
        }
        __builtin_amdgcn_s_setprio(1);
#pragma unroll
        for (int m = 0; m < 4; ++m)
#pragma unroll
            for (int n = 0; n < 4; ++n) {
                ag[m][n] = __builtin_amdgcn_mfma_i32_16x16x64_i8(af[m], gf[n], ag[m][n], 0, 0, 0);
                au[m][n] = __builtin_amdgcn_mfma_i32_16x16x64_i8(af[m], uf[n], au[m][n], 0, 0, 0);
            }
        __builtin_amdgcn_s_setprio(0);
        __builtin_amdgcn_s_barrier();              // buf[cur] free
    }

    const float sg = *sg_p, su = *su_p;
    const float dinv = 1.f / qscale[0];
    const int nko = N >> 6;
    const int rq = (lane >> 4) * 4, fc = lane & 15;
#pragma unroll
    for (int m = 0; m < 4; ++m) {
#pragma unroll
        for (int n = 0; n < 4; ++n) {
            const int col = bn + wn + n * 16 + fc;
            const float bgc = bg[col], buc = bu[col];
            const int ktc = col >> 6, kgc = (col >> 4) & 3, jc = col & 15;
#pragma unroll
            for (int r = 0; r < 4; ++r) {
                const int row = bm + wm + m * 16 + rq + r;
                const float g = (float)ag[m][n][r] * sg + bgc;
                const float u = (float)au[m][n][r] * su + buc;
                const float a = g / (1.f + __expf(-g)) * u;
                const float qv = fminf(fmaxf(rintf(a * dinv), -128.f), 127.f);
                const long addr = (((long)(row >> 7) * nko + ktc) << 13)
                                + (kgc << 11) + ((row & 127) << 4) + jc;
                out8[addr] = (signed char)(int)qv;
            }
        }
    }
}

// ---------------------------------------------------------------------------
// RoPE applied in-place to q and k, layout [B,S,NH,HD] == [B,S,H] h-major.
__global__ __launch_bounds__(256)
void rope_k(float* __restrict__ q, float* __restrict__ k)
{
    const int row = blockIdx.x;            // token index b*S+s
    const int s = row & (S_ - 1);
    float* qr = q + (long)row * H_;
    float* kr = k + (long)row * H_;
    for (int t = threadIdx.x; t < NH_ * 64; t += 256) {
        const int nh = t >> 6, i = t & 63;
        const float inv = powf(10000.f, -(float)(2 * i) * (1.f / 128.f));
        const float f = (float)s * inv;
        float sn, c;
        sincosf(f, &sn, &c);
        const int base = nh * 128 + i;
        const float q0 = qr[base], q1 = qr[base + 64];
        qr[base]      = q0 * c - q1 * sn;
        qr[base + 64] = q1 * c + q0 * sn;
        const float k0 = kr[base], k1 = kr[base + 64];
        kr[base]      = k0 * c - k1 * sn;
        kr[base + 64] = k1 * c + k0 * sn;
    }
}

// ---------------------------------------------------------------------------
// Flash attention, bf16 MFMA; epilogue fuses o/o_in_scale quant -> tiled-i8.
__global__ __launch_bounds__(256, 3)
void attn_mfma_k(const float* __restrict__ q, const float* __restrict__ k,
                 const float* __restrict__ v, signed char* __restrict__ out8,
                 const float* __restrict__ osc)
{
    __shared__ __align__(16) char lsK[8192];        // [32 krow][128 d] bf16, XOR swizzle
    __shared__ __align__(16) char lsV[10240];       // V^T [128 d][40 pitch] bf16
    __shared__ __align__(16) char lsP[4][1024];     // per-wave P [16][32] bf16, XOR swizzle

    const int tid = threadIdx.x, lane = tid & 63, wid = tid >> 6;
    const int bid = blockIdx.x;
    const int qt = 15 - (bid >> 6);                 // reversed: long blocks first
    const int bh = bid & 63;
    const int b = bh >> 5, h = bh & 31;
    const int q0 = qt * 64;
    const int qw = q0 + wid * 16;                   // this wave's first q row

    const float* qbase = q + (long)(b * S_) * H_ + (long)h * HD_;
    const float* kbase = k + (long)(b * S_) * H_ + (long)h * HD_;
    const float* vbase = v + (long)(b * S_) * H_ + (long)h * HD_;

    const int frow = lane & 15, fgrp = lane >> 4;
    const float sc = 0.08838834764831845f;          // 1/sqrt(128), folded into Q

    bf16x8 qf[4];
    {
        const float* qr = qbase + (long)(qw + frow) * H_;
#pragma unroll
        for (int c = 0; c < 4; ++c) {
            const float4 a = *(const float4*)(qr + c * 32 + fgrp * 8);
            const float4 bq = *(const float4*)(qr + c * 32 + fgrp * 8 + 4);
            bf16x8 t;
            t[0] = (short)f2bf(a.x * sc);  t[1] = (short)f2bf(a.y * sc);
            t[2] = (short)f2bf(a.z * sc);  t[3] = (short)f2bf(a.w * sc);
            t[4] = (short)f2bf(bq.x * sc); t[5] = (short)f2bf(bq.y * sc);
            t[6] = (short)f2bf(bq.z * sc); t[7] = (short)f2bf(bq.w * sc);
            qf[c] = t;
        }
    }

    f32x4 oacc[8];
#pragma unroll
    for (int n2 = 0; n2 < 8; ++n2) oacc[n2] = (f32x4){0.f, 0.f, 0.f, 0.f};
    float mr[4] = {-1e30f, -1e30f, -1e30f, -1e30f};
    float lr[4] = {0.f, 0.f, 0.f, 0.f};

    const int nt = (q0 >> 5) + 2;
    for (int kt = 0; kt < nt; ++kt) {
        if (kt) __syncthreads();
        {
            const float* kg = kbase + (long)(kt * 32) * H_;
            const float* vg = vbase + (long)(kt * 32) * H_;
#pragma unroll
            for (int i = 0; i < 4; ++i) {
                const int lin = i * 256 + tid;
                const int kr = lin >> 5;
                const int d4 = (lin & 31) * 4;
                const float4 kv = *(const float4*)(kg + (long)kr * H_ + d4);
                const float4 vv = *(const float4*)(vg + (long)kr * H_ + d4);
                ushort4 kb;
                kb.x = f2bf(kv.x); kb.y = f2bf(kv.y); kb.z = f2bf(kv.z); kb.w = f2bf(kv.w);
                *(ushort4*)(lsK + kr * 256 + ((d4 * 2) ^ ((kr & 7) << 4))) = kb;
                *(unsigned short*)(lsV + (d4 + 0) * 80 + kr * 2) = f2bf(vv.x);
                *(unsigned short*)(lsV + (d4 + 1) * 80 + kr * 2) = f2bf(vv.y);
                *(unsigned short*)(lsV + (d4 + 2) * 80 + kr * 2) = f2bf(vv.z);
                *(unsigned short*)(lsV + (d4 + 3) * 80 + kr * 2) = f2bf(vv.w);
            }
        }
        __syncthreads();

        if (kt * 32 <= qw + 15) {
            f32x4 s0 = (f32x4){0.f, 0.f, 0.f, 0.f};
            f32x4 s1 = (f32x4){0.f, 0.f, 0.f, 0.f};
            const int swz = (frow & 7) << 4;
#pragma unroll
            for (int c = 0; c < 4; ++c) {
                const int dby = c * 64 + fgrp * 16;
                const bf16x8 kfA = *(const bf16x8*)(lsK + frow * 256 + (dby ^ swz));
                const bf16x8 kfB = *(const bf16x8*)(lsK + (frow + 16) * 256 + (dby ^ swz));
                s0 = __builtin_amdgcn_mfma_f32_16x16x32_bf16(qf[c], kfA, s0, 0, 0, 0);
                s1 = __builtin_amdgcn_mfma_f32_16x16x32_bf16(qf[c], kfB, s1, 0, 0, 0);
            }

            const int colg0 = kt * 32 + frow;
            float cf[4];
#pragma unroll
            for (int r = 0; r < 4; ++r) {
                const int rowg = qw + fgrp * 4 + r;
                const float a0 = (colg0 <= rowg) ? s0[r] : -1e30f;
                const float a1 = (colg0 + 16 <= rowg) ? s1[r] : -1e30f;
                float mx = fmaxf(a0, a1);
#pragma unroll
                for (int off2 = 1; off2 < 16; off2 <<= 1) mx = fmaxf(mx, __shfl_xor(mx, off2));
                const float mnew = fmaxf(mr[r], mx);
                cf[r] = __expf(mr[r] - mnew);
                mr[r] = mnew;
                const float p0 = __expf(a0 - mnew);
                const float p1 = __expf(a1 - mnew);
                float sm = p0 + p1;
#pragma unroll
                for (int off2 = 1; off2 < 16; off2 <<= 1) sm += __shfl_xor(sm, off2);
                lr[r] = lr[r] * cf[r] + sm;
                const int row = fgrp * 4 + r;
                const int psw = (row & 3) << 4;
                *(unsigned short*)(lsP[wid] + row * 64 + ((frow * 2) ^ psw)) = f2bf(p0);
                *(unsigned short*)(lsP[wid] + row * 64 + (((16 + frow) * 2) ^ psw)) = f2bf(p1);
            }
#pragma unroll
            for (int n2 = 0; n2 < 8; ++n2) {
#pragma unroll
                for (int r = 0; r < 4; ++r) oacc[n2][r] *= cf[r];
            }
            const bf16x8 pf = *(const bf16x8*)(lsP[wid] + frow * 64 + ((fgrp * 16) ^ ((frow & 3) << 4)));
#pragma unroll
            for (int n2 = 0; n2 < 8; ++n2) {
                const bf16x8 vf = *(const bf16x8*)(lsV + (n2 * 16 + frow) * 80 + fgrp * 16);
                oacc[n2] = __builtin_amdgcn_mfma_f32_16x16x32_bf16(pf, vf, oacc[n2], 0, 0, 0);
            }
        }
    }

    // epilogue: o = oacc/l, q8 = clip(rint(o/osc)) -> tiled-i8 (nk = 64)
    const float oinv = 1.f / osc[0];
    float inv[4];
#pragma unroll
    for (int r = 0; r < 4; ++r) inv[r] = 1.f / lr[r];
#pragma unroll
    for (int n2 = 0; n2 < 8; ++n2) {
        const int kk = h * 128 + n2 * 16 + frow;
        const int ktc = kk >> 6, kgc = (kk >> 4) & 3, jc = kk & 15;
#pragma unroll
        for (int r = 0; r < 4; ++r) {
            const int rowt = b * S_ + qw + fgrp * 4 + r;
            const float ov = oacc[n2][r] * inv[r];
            const float qv = fminf(fmaxf(rintf(ov * oinv), -128.f), 127.f);
            const long addr = (((long)(rowt >> 7) * 64 + ktc) << 13)
                            + (kgc << 11) + ((rowt & 127) << 4) + jc;
            out8[addr] = (signed char)(int)qv;
        }
    }
}

// ---------------------------------------------------------------------------
extern "C" void kernel_launch(void* const* d_in, const int* in_sizes, int n_in,
                              void* d_out, int out_size, void* d_ws, size_t ws_size,
                              hipStream_t stream)
{
    const float* hidden = (const float*)d_in[0];
    const float* ln1 = (const float*)d_in[1];
    const float* ln2 = (const float*)d_in[2];
    const int* Wq = (const int*)d_in[3];
    const int* Wk = (const int*)d_in[4];
    const int* Wv = (const int*)d_in[5];
    const int* Wo = (const int*)d_in[6];
    const int* Wg = (const int*)d_in[7];
    const int* Wu = (const int*)d_in[8];
    const int* Wd = (const int*)d_in[9];
    const float* bq = (const float*)d_in[10];
    const float* bk = (const float*)d_in[11];
    const float* bv = (const float*)d_in[12];
    const float* bo = (const float*)d_in[13];
    const float* bg = (const float*)d_in[14];
    const float* bu = (const float*)d_in[15];
    const float* bd = (const float*)d_in[16];
    const float* sq = (const float*)d_in[17];
    const float* sk = (const float*)d_in[18];
    const float* sv = (const float*)d_in[19];
    const float* so = (const float*)d_in[20];
    const float* sg = (const float*)d_in[21];
    const float* su = (const float*)d_in[22];
    const float* sd = (const float*)d_in[23];
    const float* o_sc = (const float*)d_in[24];
    const float* d_sc = (const float*)d_in[25];

    // workspace layout (MiB offsets, peak 229 MiB):
    //  [0,8)     HQ8 tiled i8 (hq / oq / hq2, sequential reuse)
    //  [8,30)    AQ8 tiled i8 (2048 x 11008)
    //  [30,74)   WPa: Wq -> Wv -> Wg packed (44 MiB)
    //  [74,106)  Qb fp32 -> (post-attn) Hb
    //  [106,138) Kb ; [138,170) Vb   (dead after attn)
    //  [170,186) WPb: Wk -> Wo packed (16 MiB)
    //  [186,229) WPu: Wu packed (43 MiB)
    //  [106,149) WPd: Wd packed (43 MiB, over dead K/V)
    char* ws = (char*)d_ws;
    signed char* HQ8 = (signed char*)ws;
    signed char* AQ8 = (signed char*)(ws + ((size_t)8 << 20));
    signed char* WPa = (signed char*)(ws + ((size_t)30 << 20));
    float* Qb = (float*)(ws + ((size_t)74 << 20));
    float* Kb = (float*)(ws + ((size_t)106 << 20));
    float* Vb = (float*)(ws + ((size_t)138 << 20));
    signed char* WPb = (signed char*)(ws + ((size_t)170 << 20));
    signed char* WPu = (signed char*)(ws + ((size_t)186 << 20));
    signed char* WPd = (signed char*)(ws + ((size_t)106 << 20));
    float* Hb = Qb;
    float* out = (float*)d_out;

    const dim3 blk(256);
    const int gxH = R_ / 128;                 // 16 row blocks
    const int nwgH = gxH * (H_ / 128);        // 512
    const int nwgI = gxH * (I_ / 128);        // 1376
    const dim3 gpH(H_ / 64, H_ / 128);        // pack grids: (nk, N/128)
    const dim3 gpI(H_ / 64, I_ / 128);
    const dim3 gpD(I_ / 64, H_ / 128);

    rmsnorm_quant_k<<<R_, blk, 0, stream>>>(hidden, ln1, HQ8);

    packW_k<<<gpH, blk, 0, stream>>>(Wq, WPa, H_);
    gemm_i8t<<<nwgH, blk, 0, stream>>>(HQ8, WPa, sq, bq, nullptr, Qb, H_, H_, gxH);
    packW_k<<<gpH, blk, 0, stream>>>(Wk, WPb, H_);
    gemm_i8t<<<nwgH, blk, 0, stream>>>(HQ8, WPb, sk, bk, nullptr, Kb, H_, H_, gxH);
    packW_k<<<gpH, blk, 0, stream>>>(Wv, WPa, H_);
    gemm_i8t<<<nwgH, blk, 0, stream>>>(HQ8, WPa, sv, bv, nullptr, Vb, H_, H_, gxH);

    rope_k<<<R_, blk, 0, stream>>>(Qb, Kb);
    attn_mfma_k<<<B_ * NH_ * (S_ / 64), blk, 0, stream>>>(Qb, Kb, Vb, HQ8, o_sc);

    packW_k<<<gpH, blk, 0, stream>>>(Wo, WPb, H_);
    gemm_i8t<<<nwgH, blk, 0, stream>>>(HQ8, WPb, so, bo, hidden, Hb, H_, H_, gxH);

    rmsnorm_quant_k<<<R_, blk, 0, stream>>>(Hb, ln2, HQ8);

    packW_k<<<gpI, blk, 0, stream>>>(Wg, WPa, H_);
    packW_k<<<gpI, blk, 0, stream>>>(Wu, WPu, H_);
    gemm_gu<<<nwgI, blk, 0, stream>>>(HQ8, WPa, WPu, sg, bg, su, bu,
                                      d_sc, AQ8, I_, H_, gxH);
    packW_k<<<gpD, blk, 0, stream>>>(Wd, WPd, I_);
    gemm_i8t<<<nwgH, blk, 0, stream>>>(AQ8, WPd, sd, bd, Hb, out, H_, I_, gxH);
}

// Round 16
// 930.146 us; speedup vs baseline: 1.0615x; 1.0108x over previous
//
#include <hip/hip_runtime.h>
#include <math.h>

#define B_  2
#define S_  1024
#define H_  4096
#define NH_ 32
#define HD_ 128
#define I_  11008
#define R_  2048   // B*S tokens

typedef __attribute__((ext_vector_type(4))) int i32x4;
typedef __attribute__((ext_vector_type(4))) float f32x4;
typedef __attribute__((ext_vector_type(8))) short bf16x8;

// Tiled int8 layout (v1, validated): for matrix [Rows][K], nk = K/64;
// tile (rb, kt) is 8192 B at ((rb*nk + kt)<<13), internally
// [kgrp 0..3][row 0..127][16B]  (kgrp = (k%64)/16).
//
// r14 LESSON: kernels with hand-counted s_waitcnt vmcnt(N) must never spill —
// scratch buffer ops count toward vmcnt. Keep launch_bounds at the no-spill
// occupancy (gemm_gu: (256,2)).
// r7 LESSON: global_load_lds global src is PER-LANE; LDS dest is wave-uniform.

// ---------------------------------------------------------------------------
__device__ __forceinline__ void gload_lds16(const void* g, void* l) {
    __builtin_amdgcn_global_load_lds(
        (const __attribute__((address_space(1))) unsigned int*)g,
        (__attribute__((address_space(3))) unsigned int*)l, 16, 0, 0);
}

__device__ __forceinline__ unsigned short f2bf(float f) {
    unsigned int u = __float_as_uint(f);
    u += 0x7fffu + ((u >> 16) & 1u);   // RNE
    return (unsigned short)(u >> 16);
}

// ---------------------------------------------------------------------------
// Pack one W (int32 [N][K]) into tiled-i8. Grid: (K/64, N/128).
__global__ __launch_bounds__(256)
void packW_k(const int* __restrict__ W, signed char* __restrict__ out, const int K)
{
    const int kt = blockIdx.x, cb = blockIdx.y, nk = gridDim.x;
    const int t = threadIdx.x;
    int* otile = (int*)(out + ((long)(cb * nk + kt) << 13));
#pragma unroll
    for (int i = 0; i < 8; ++i) {
        const int o = i * 256 + t;                 // int32 index in tile
        const int g = o >> 9, r = (o >> 2) & 127, jj = o & 3;
        const int4 w4 = *(const int4*)(W + (long)(cb * 128 + r) * K + kt * 64 + g * 16 + jj * 4);
        otile[o] = (w4.x & 255) | ((w4.y & 255) << 8) | ((w4.z & 255) << 16) | (w4.w << 24);
    }
}

// ---------------------------------------------------------------------------
// RMSNorm + int8 quant (scale folded into w). Output in tiled-i8 (nk=64).
__global__ __launch_bounds__(256)
void rmsnorm_quant_k(const float* __restrict__ x, const float* __restrict__ w,
                     signed char* __restrict__ out)
{
    __shared__ float red[4];
    const int tid = threadIdx.x;
    const long row = blockIdx.x;
    const float4* xr = (const float4*)(x + row * H_);
    float4 xv[4];
    float ss = 0.f;
#pragma unroll
    for (int i = 0; i < 4; ++i) {
        xv[i] = xr[tid + i * 256];
        ss += xv[i].x * xv[i].x + xv[i].y * xv[i].y
            + xv[i].z * xv[i].z + xv[i].w * xv[i].w;
    }
#pragma unroll
    for (int off = 32; off; off >>= 1) ss += __shfl_xor(ss, off);
    if ((tid & 63) == 0) red[tid >> 6] = ss;
    __syncthreads();
    const float tot = red[0] + red[1] + red[2] + red[3];
    const float sc = 1.f / sqrtf(tot * (1.f / (float)H_) + 1e-6f);
    const float4* wr = (const float4*)w;
    int* ob = (int*)out;
    const long rb = row >> 7;
    const int rr = (int)(row & 127);
#pragma unroll
    for (int i = 0; i < 4; ++i) {
        const float4 wv = wr[tid + i * 256];
        const int b0 = (int)fminf(fmaxf(rintf(xv[i].x * sc * wv.x), -128.f), 127.f);
        const int b1 = (int)fminf(fmaxf(rintf(xv[i].y * sc * wv.y), -128.f), 127.f);
        const int b2 = (int)fminf(fmaxf(rintf(xv[i].z * sc * wv.z), -128.f), 127.f);
        const int b3 = (int)fminf(fmaxf(rintf(xv[i].w * sc * wv.w), -128.f), 127.f);
        const int packed = (b0 & 255) | ((b1 & 255) << 8) | ((b2 & 255) << 16) | (b3 << 24);
        const int j4 = tid + i * 256;              // int32 group within row
        const long a32 = ((rb * 64 + (j4 >> 4)) << 11) + (((j4 >> 2) & 3) << 9)
                       + (rr << 2) + (j4 & 3);
        ob[a32] = packed;
    }
}

// ---------------------------------------------------------------------------
// int8 GEMM (round-8 validated): BK=128 double-step, depth-2 ring, counted
// vmcnt(8), 64KB LDS -> 2 blocks/CU. Wave-out 64x64 (acc[4][4]).
// MODE 0: C fp32 = acc*s + bias (+residual).  MODE 2: Cbf bf16 (for V).
template<int MODE>
__global__ __launch_bounds__(256, 2)
void gemm_i8t(const signed char* __restrict__ A8, const signed char* __restrict__ W8,
              const float* __restrict__ scale_ptr, const float* __restrict__ bias,
              const float* __restrict__ residual, float* __restrict__ C,
              unsigned short* __restrict__ Cbf,
              const int N, const int K, const int gx)
{
    __shared__ __align__(16) signed char lsA[2][16384];
    __shared__ __align__(16) signed char lsB[2][16384];

    int bid = blockIdx.x;
    {   // bijective XCD chunked remap (m204)
        const int nwg = gridDim.x;
        const int q = nwg >> 3, r = nwg & 7;
        const int xcd = bid & 7, idx = bid >> 3;
        bid = (xcd < r) ? (xcd * (q + 1) + idx)
                        : (r * (q + 1) + (xcd - r) * q + idx);
    }
    const int bx = bid % gx, by = bid / gx;

    const int tid  = threadIdx.x;
    const int lane = tid & 63, wid = tid >> 6;
    const int bm = bx << 7, bn = by << 7;
    const int wm = (wid >> 1) << 6, wn = (wid & 1) << 6;

    i32x4 acc[4][4];
#pragma unroll
    for (int m = 0; m < 4; ++m)
#pragma unroll
        for (int n = 0; n < 4; ++n) acc[m][n] = (i32x4){0, 0, 0, 0};

    const int nk  = K >> 6;
    const int nk2 = K >> 7;
    const signed char* abase = A8 + ((long)bx * nk << 13);
    const signed char* bbase = W8 + ((long)by * nk << 13);
    const int sgg = wid * 4096 + lane * 16;        // GLOBAL src: per-lane
    const int sgl = wid * 4096;                    // LDS dest: wave-uniform

#pragma unroll
    for (int c = 0; c < 4; ++c) {
        gload_lds16(abase + sgg + c * 1024, lsA[0] + sgl + c * 1024);
        gload_lds16(bbase + sgg + c * 1024, lsB[0] + sgl + c * 1024);
    }

    for (int kt = 0; kt < nk2; ++kt) {
        const int cur = kt & 1, nxt = cur ^ 1;
        if (kt + 1 < nk2) {
            const signed char* at = abase + ((long)(kt + 1) << 14);
            const signed char* bt = bbase + ((long)(kt + 1) << 14);
#pragma unroll
            for (int c = 0; c < 4; ++c) {
                gload_lds16(at + sgg + c * 1024, lsA[nxt] + sgl + c * 1024);
                gload_lds16(bt + sgg + c * 1024, lsB[nxt] + sgl + c * 1024);
            }
            asm volatile("s_waitcnt vmcnt(8)" ::: "memory");
        } else {
            asm volatile("s_waitcnt vmcnt(0)" ::: "memory");
        }
        __builtin_amdgcn_s_barrier();

        const int kg = (lane >> 4) * 2048, fr = (lane & 15) * 16;
#pragma unroll
        for (int s = 0; s < 2; ++s) {
            const int off = s * 8192;
            i32x4 af[4], bf[4];
#pragma unroll
            for (int m = 0; m < 4; ++m)
                af[m] = *(const i32x4*)(lsA[cur] + off + kg + wm * 16 + m * 256 + fr);
#pragma unroll
            for (int n = 0; n < 4; ++n)
                bf[n] = *(const i32x4*)(lsB[cur] + off + kg + wn * 16 + n * 256 + fr);
            __builtin_amdgcn_s_setprio(1);
#pragma unroll
            for (int m = 0; m < 4; ++m)
#pragma unroll
                for (int n = 0; n < 4; ++n)
                    acc[m][n] = __builtin_amdgcn_mfma_i32_16x16x64_i8(af[m], bf[n], acc[m][n], 0, 0, 0);
            __builtin_amdgcn_s_setprio(0);
        }
        __builtin_amdgcn_s_barrier();
    }

    const float s = *scale_ptr;
    const int rq = (lane >> 4) * 4, fc = lane & 15;
#pragma unroll
    for (int m = 0; m < 4; ++m) {
#pragma unroll
        for (int n = 0; n < 4; ++n) {
            const int col = bn + wn + n * 16 + fc;
            const float bcol = bias[col];
#pragma unroll
            for (int r = 0; r < 4; ++r) {
                const int row = bm + wm + m * 16 + rq + r;
                const float v = (float)acc[m][n][r] * s + bcol;
                if (MODE == 0) {
                    float vv = v;
                    if (residual) vv += residual[(long)row * N + col];
                    C[(long)row * N + col] = vv;
                } else {
                    Cbf[(long)row * N + col] = f2bf(v);
                }
            }
        }
    }
}

// ---------------------------------------------------------------------------
// Fused gate+up int8 GEMM (r11 validated). (256,2) — do NOT raise (r14).
__global__ __launch_bounds__(256, 2)
void gemm_gu(const signed char* __restrict__ A8, const signed char* __restrict__ G8,
             const signed char* __restrict__ U8,
             const float* __restrict__ sg_p, const float* __restrict__ bg,
             const float* __restrict__ su_p, const float* __restrict__ bu,
             const float* __restrict__ qscale, signed char* __restrict__ out8,
             const int N, const int K, const int gx)
{
    __shared__ __align__(16) signed char lsA[2][8192];
    __shared__ __align__(16) signed char lsG[2][8192];
    __shared__ __align__(16) signed char lsU[2][8192];

    int bid = blockIdx.x;
    {   // bijective XCD chunked remap
        const int nwg = gridDim.x;
        const int q = nwg >> 3, r = nwg & 7;
        const int xcd = bid & 7, idx = bid >> 3;
        bid = (xcd < r) ? (xcd * (q + 1) + idx)
                        : (r * (q + 1) + (xcd - r) * q + idx);
    }
    const int bx = bid % gx, by = bid / gx;
    const int tid = threadIdx.x, lane = tid & 63, wid = tid >> 6;
    const int bm = bx << 7, bn = by << 7;
    const int wm = (wid >> 1) << 6, wn = (wid & 1) << 6;

    i32x4 ag[4][4], au[4][4];
#pragma unroll
    for (int m = 0; m < 4; ++m)
#pragma unroll
        for (int n = 0; n < 4; ++n) {
            ag[m][n] = (i32x4){0, 0, 0, 0};
            au[m][n] = (i32x4){0, 0, 0, 0};
        }

    const int nk = K >> 6;
    const signed char* abase = A8 + ((long)bx * nk << 13);
    const signed char* gbase = G8 + ((long)by * nk << 13);
    const signed char* ubase = U8 + ((long)by * nk << 13);
    const int sgg = wid * 2048 + lane * 16;        // GLOBAL src: per-lane
    const int sgl = wid * 2048;                    // LDS dest: wave-uniform

#pragma unroll
    for (int c = 0; c < 2; ++c) {
        gload_lds16(abase + sgg + c * 1024, lsA[0] + sgl + c * 1024);
        gload_lds16(gbase + sgg + c * 1024, lsG[0] + sgl + c * 1024);
        gload_lds16(ubase + sgg + c * 1024, lsU[0] + sgl + c * 1024);
    }

    for (int kt = 0; kt < nk; ++kt) {
        const int cur = kt & 1, nxt = cur ^ 1;
        if (kt + 1 < nk) {
            const signed char* at = abase + ((long)(kt + 1) << 13);
            const signed char* gt = gbase + ((long)(kt + 1) << 13);
            const signed char* ut = ubase + ((long)(kt + 1) << 13);
#pragma unroll
            for (int c = 0; c < 2; ++c) {
                gload_lds16(at + sgg + c * 1024, lsA[nxt] + sgl + c * 1024);
                gload_lds16(gt + sgg + c * 1024, lsG[nxt] + sgl + c * 1024);
                gload_lds16(ut + sgg + c * 1024, lsU[nxt] + sgl + c * 1024);
            }
            asm volatile("s_waitcnt vmcnt(6)" ::: "memory");   // drain step kt's 6
        } else {
            asm volatile("s_waitcnt vmcnt(0)" ::: "memory");
        }
        __builtin_amdgcn_s_barrier();              // step kt visible

        const int kg = (lane >> 4) * 2048, fr = (lane & 15) * 16;
        i32x4 af[4], gf[4], uf[4];
#pragma unroll
        for (int m = 0; m < 4; ++m)
            af[m] = *(const i32x4*)(lsA[cur] + kg + wm * 16 + m * 256 + fr);
#pragma unroll
        for (int n = 0; n < 4; ++n) {
            gf[n] = *(const i32x4*)(lsG[cur] + kg + wn * 16 + n * 256 + fr);
            uf[n] = *(const i32x4*)(lsU[cur] + kg + wn * 16 + n * 256 + fr);
        }
        __builtin_amdgcn_s_setprio(1);
#pragma unroll
        for (int m = 0; m < 4; ++m)
#pragma unroll
            for (int n = 0; n < 4; ++n) {
                ag[m][n] = __builtin_amdgcn_mfma_i32_16x16x64_i8(af[m], gf[n], ag[m][n], 0, 0, 0);
                au[m][n] = __builtin_amdgcn_mfma_i32_16x16x64_i8(af[m], uf[n], au[m][n], 0, 0, 0);
            }
        __builtin_amdgcn_s_setprio(0);
        __builtin_amdgcn_s_barrier();              // buf[cur] free
    }

    const float sg = *sg_p, su = *su_p;
    const float dinv = 1.f / qscale[0];
    const int nko = N >> 6;
    const int rq = (lane >> 4) * 4, fc = lane & 15;
#pragma unroll
    for (int m = 0; m < 4; ++m) {
#pragma unroll
        for (int n = 0; n < 4; ++n) {
            const int col = bn + wn + n * 16 + fc;
            const float bgc = bg[col], buc = bu[col];
            const int ktc = col >> 6, kgc = (col >> 4) & 3, jc = col & 15;
#pragma unroll
            for (int r = 0; r < 4; ++r) {
                const int row = bm + wm + m * 16 + rq + r;
                const float g = (float)ag[m][n][r] * sg + bgc;
                const float u = (float)au[m][n][r] * su + buc;
                const float a = g / (1.f + __expf(-g)) * u;
                const float qv = fminf(fmaxf(rintf(a * dinv), -128.f), 127.f);
                const long addr = (((long)(row >> 7) * nko + ktc) << 13)
                                + (kgc << 11) + ((row & 127) << 4) + jc;
                out8[addr] = (signed char)(int)qv;
            }
        }
    }
}

// ---------------------------------------------------------------------------
// RoPE: Q in-place fp32; K read fp32 -> roped -> written bf16 (same f2bf value
// attn previously computed per-tile; numerics identical, half the traffic).
__global__ __launch_bounds__(256)
void rope_k(float* __restrict__ q, const float* __restrict__ kin,
            unsigned short* __restrict__ kbf)
{
    const int row = blockIdx.x;            // token index b*S+s
    const int s = row & (S_ - 1);
    float* qr = q + (long)row * H_;
    const float* kr = kin + (long)row * H_;
    unsigned short* ko = kbf + (long)row * H_;
    for (int t = threadIdx.x; t < NH_ * 64; t += 256) {
        const int nh = t >> 6, i = t & 63;
        const float inv = powf(10000.f, -(float)(2 * i) * (1.f / 128.f));
        const float f = (float)s * inv;
        float sn, c;
        sincosf(f, &sn, &c);
        const int base = nh * 128 + i;
        const float q0 = qr[base], q1 = qr[base + 64];
        qr[base]      = q0 * c - q1 * sn;
        qr[base + 64] = q1 * c + q0 * sn;
        const float k0 = kr[base], k1 = kr[base + 64];
        ko[base]      = f2bf(k0 * c - k1 * sn);
        ko[base + 64] = f2bf(k1 * c + k0 * sn);
    }
}

// ---------------------------------------------------------------------------
// Flash attention, bf16 MFMA; K/V arrive pre-converted bf16 (half traffic,
// no cvt in staging). Epilogue fuses o/o_in_scale quant -> tiled-i8.
__global__ __launch_bounds__(256, 3)
void attn_mfma_k(const float* __restrict__ q, const unsigned short* __restrict__ kbf,
                 const unsigned short* __restrict__ vbf, signed char* __restrict__ out8,
                 const float* __restrict__ osc)
{
    __shared__ __align__(16) char lsK[8192];        // [32 krow][128 d] bf16, XOR swizzle
    __shared__ __align__(16) char lsV[10240];       // V^T [128 d][40 pitch] bf16
    __shared__ __align__(16) char lsP[4][1024];     // per-wave P [16][32] bf16, XOR swizzle

    const int tid = threadIdx.x, lane = tid & 63, wid = tid >> 6;
    const int bid = blockIdx.x;
    const int qt = 15 - (bid >> 6);                 // reversed: long blocks first
    const int bh = bid & 63;
    const int b = bh >> 5, h = bh & 31;
    const int q0 = qt * 64;
    const int qw = q0 + wid * 16;                   // this wave's first q row

    const float* qbase = q + (long)(b * S_) * H_ + (long)h * HD_;
    const unsigned short* kbase = kbf + (long)(b * S_) * H_ + (long)h * HD_;
    const unsigned short* vbase = vbf + (long)(b * S_) * H_ + (long)h * HD_;

    const int frow = lane & 15, fgrp = lane >> 4;
    const float sc = 0.08838834764831845f;          // 1/sqrt(128), folded into Q

    bf16x8 qf[4];
    {
        const float* qr = qbase + (long)(qw + frow) * H_;
#pragma unroll
        for (int c = 0; c < 4; ++c) {
            const float4 a = *(const float4*)(qr + c * 32 + fgrp * 8);
            const float4 bq = *(const float4*)(qr + c * 32 + fgrp * 8 + 4);
            bf16x8 t;
            t[0] = (short)f2bf(a.x * sc);  t[1] = (short)f2bf(a.y * sc);
            t[2] = (short)f2bf(a.z * sc);  t[3] = (short)f2bf(a.w * sc);
            t[4] = (short)f2bf(bq.x * sc); t[5] = (short)f2bf(bq.y * sc);
            t[6] = (short)f2bf(bq.z * sc); t[7] = (short)f2bf(bq.w * sc);
            qf[c] = t;
        }
    }

    f32x4 oacc[8];
#pragma unroll
    for (int n2 = 0; n2 < 8; ++n2) oacc[n2] = (f32x4){0.f, 0.f, 0.f, 0.f};
    float mr[4] = {-1e30f, -1e30f, -1e30f, -1e30f};
    float lr[4] = {0.f, 0.f, 0.f, 0.f};

    const int nt = (q0 >> 5) + 2;
    for (int kt = 0; kt < nt; ++kt) {
        if (kt) __syncthreads();
        {
            const unsigned short* kg = kbase + (long)(kt * 32) * H_;
            const unsigned short* vg = vbase + (long)(kt * 32) * H_;
#pragma unroll
            for (int i = 0; i < 2; ++i) {
                const int lin = i * 256 + tid;      // 512 units of 8 bf16
                const int kr = lin >> 4;            // 0..31
                const int d8 = (lin & 15) * 8;      // 0..120
                const bf16x8 kv = *(const bf16x8*)(kg + (long)kr * H_ + d8);
                *(bf16x8*)(lsK + kr * 256 + ((d8 * 2) ^ ((kr & 7) << 4))) = kv;
                const bf16x8 vv = *(const bf16x8*)(vg + (long)kr * H_ + d8);
#pragma unroll
                for (int e = 0; e < 8; ++e)
                    *(unsigned short*)(lsV + (d8 + e) * 80 + kr * 2) = (unsigned short)vv[e];
            }
        }
        __syncthreads();

        if (kt * 32 <= qw + 15) {
            f32x4 s0 = (f32x4){0.f, 0.f, 0.f, 0.f};
            f32x4 s1 = (f32x4){0.f, 0.f, 0.f, 0.f};
            const int swz = (frow & 7) << 4;
#pragma unroll
            for (int c = 0; c < 4; ++c) {
                const int dby = c * 64 + fgrp * 16;
                const bf16x8 kfA = *(const bf16x8*)(lsK + frow * 256 + (dby ^ swz));
                const bf16x8 kfB = *(const bf16x8*)(lsK + (frow + 16) * 256 + (dby ^ swz));
                s0 = __builtin_amdgcn_mfma_f32_16x16x32_bf16(qf[c], kfA, s0, 0, 0, 0);
                s1 = __builtin_amdgcn_mfma_f32_16x16x32_bf16(qf[c], kfB, s1, 0, 0, 0);
            }

            const int colg0 = kt * 32 + frow;
            float cf[4];
#pragma unroll
            for (int r = 0; r < 4; ++r) {
                const int rowg = qw + fgrp * 4 + r;
                const float a0 = (colg0 <= rowg) ? s0[r] : -1e30f;
                const float a1 = (colg0 + 16 <= rowg) ? s1[r] : -1e30f;
                float mx = fmaxf(a0, a1);
#pragma unroll
                for (int off2 = 1; off2 < 16; off2 <<= 1) mx = fmaxf(mx, __shfl_xor(mx, off2));
                const float mnew = fmaxf(mr[r], mx);
                cf[r] = __expf(mr[r] - mnew);
                mr[r] = mnew;
                const float p0 = __expf(a0 - mnew);
                const float p1 = __expf(a1 - mnew);
                float sm = p0 + p1;
#pragma unroll
                for (int off2 = 1; off2 < 16; off2 <<= 1) sm += __shfl_xor(sm, off2);
                lr[r] = lr[r] * cf[r] + sm;
                const int row = fgrp * 4 + r;
                const int psw = (row & 3) << 4;
                *(unsigned short*)(lsP[wid] + row * 64 + ((frow * 2) ^ psw)) = f2bf(p0);
                *(unsigned short*)(lsP[wid] + row * 64 + (((16 + frow) * 2) ^ psw)) = f2bf(p1);
            }
#pragma unroll
            for (int n2 = 0; n2 < 8; ++n2) {
#pragma unroll
                for (int r = 0; r < 4; ++r) oacc[n2][r] *= cf[r];
            }
            const bf16x8 pf = *(const bf16x8*)(lsP[wid] + frow * 64 + ((fgrp * 16) ^ ((frow & 3) << 4)));
#pragma unroll
            for (int n2 = 0; n2 < 8; ++n2) {
                const bf16x8 vf = *(const bf16x8*)(lsV + (n2 * 16 + frow) * 80 + fgrp * 16);
                oacc[n2] = __builtin_amdgcn_mfma_f32_16x16x32_bf16(pf, vf, oacc[n2], 0, 0, 0);
            }
        }
    }

    // epilogue: o = oacc/l, q8 = clip(rint(o/osc)) -> tiled-i8 (nk = 64)
    const float oinv = 1.f / osc[0];
    float inv[4];
#pragma unroll
    for (int r = 0; r < 4; ++r) inv[r] = 1.f / lr[r];
#pragma unroll
    for (int n2 = 0; n2 < 8; ++n2) {
        const int kk = h * 128 + n2 * 16 + frow;
        const int ktc = kk >> 6, kgc = (kk >> 4) & 3, jc = kk & 15;
#pragma unroll
        for (int r = 0; r < 4; ++r) {
            const int rowt = b * S_ + qw + fgrp * 4 + r;
            const float ov = oacc[n2][r] * inv[r];
            const float qv = fminf(fmaxf(rintf(ov * oinv), -128.f), 127.f);
            const long addr = (((long)(rowt >> 7) * 64 + ktc) << 13)
                            + (kgc << 11) + ((rowt & 127) << 4) + jc;
            out8[addr] = (signed char)(int)qv;
        }
    }
}

// ---------------------------------------------------------------------------
extern "C" void kernel_launch(void* const* d_in, const int* in_sizes, int n_in,
                              void* d_out, int out_size, void* d_ws, size_t ws_size,
                              hipStream_t stream)
{
    const float* hidden = (const float*)d_in[0];
    const float* ln1 = (const float*)d_in[1];
    const float* ln2 = (const float*)d_in[2];
    const int* Wq = (const int*)d_in[3];
    const int* Wk = (const int*)d_in[4];
    const int* Wv = (const int*)d_in[5];
    const int* Wo = (const int*)d_in[6];
    const int* Wg = (const int*)d_in[7];
    const int* Wu = (const int*)d_in[8];
    const int* Wd = (const int*)d_in[9];
    const float* bq = (const float*)d_in[10];
    const float* bk = (const float*)d_in[11];
    const float* bv = (const float*)d_in[12];
    const float* bo = (const float*)d_in[13];
    const float* bg = (const float*)d_in[14];
    const float* bu = (const float*)d_in[15];
    const float* bd = (const float*)d_in[16];
    const float* sq = (const float*)d_in[17];
    const float* sk = (const float*)d_in[18];
    const float* sv = (const float*)d_in[19];
    const float* so = (const float*)d_in[20];
    const float* sg = (const float*)d_in[21];
    const float* su = (const float*)d_in[22];
    const float* sd = (const float*)d_in[23];
    const float* o_sc = (const float*)d_in[24];
    const float* d_sc = (const float*)d_in[25];

    // workspace layout (MiB offsets, peak 229 MiB):
    //  [0,8)     HQ8 tiled i8 (hq / oq / hq2, sequential reuse)
    //  [8,30)    AQ8 tiled i8 (2048 x 11008)
    //  [30,74)   WPa: Wq -> Wv -> Wg packed (44 MiB)
    //  [74,106)  Qb fp32 -> (post-attn) Hb
    //  [106,138) Kb fp32 (dead after rope)
    //  [138,154) Vbf bf16 ; [154,170) Kbf bf16   (dead after attn)
    //  [170,186) WPb: Wk -> Wo packed (16 MiB)
    //  [186,229) WPu: Wu packed (43 MiB)
    //  [106,149) WPd: Wd packed (43 MiB, over dead Kb/Vbf, packed after attn)
    char* ws = (char*)d_ws;
    signed char* HQ8 = (signed char*)ws;
    signed char* AQ8 = (signed char*)(ws + ((size_t)8 << 20));
    signed char* WPa = (signed char*)(ws + ((size_t)30 << 20));
    float* Qb = (float*)(ws + ((size_t)74 << 20));
    float* Kb = (float*)(ws + ((size_t)106 << 20));
    unsigned short* Vbf = (unsigned short*)(ws + ((size_t)138 << 20));
    unsigned short* Kbf = (unsigned short*)(ws + ((size_t)154 << 20));
    signed char* WPb = (signed char*)(ws + ((size_t)170 << 20));
    signed char* WPu = (signed char*)(ws + ((size_t)186 << 20));
    signed char* WPd = (signed char*)(ws + ((size_t)106 << 20));
    float* Hb = Qb;
    float* out = (float*)d_out;

    const dim3 blk(256);
    const int gxH = R_ / 128;                 // 16 row blocks
    const int nwgH = gxH * (H_ / 128);        // 512
    const int nwgI = gxH * (I_ / 128);        // 1376
    const dim3 gpH(H_ / 64, H_ / 128);        // pack grids: (nk, N/128)
    const dim3 gpI(H_ / 64, I_ / 128);
    const dim3 gpD(I_ / 64, H_ / 128);

    rmsnorm_quant_k<<<R_, blk, 0, stream>>>(hidden, ln1, HQ8);

    packW_k<<<gpH, blk, 0, stream>>>(Wq, WPa, H_);
    gemm_i8t<0><<<nwgH, blk, 0, stream>>>(HQ8, WPa, sq, bq, nullptr, Qb, nullptr, H_, H_, gxH);
    packW_k<<<gpH, blk, 0, stream>>>(Wk, WPb, H_);
    gemm_i8t<0><<<nwgH, blk, 0, stream>>>(HQ8, WPb, sk, bk, nullptr, Kb, nullptr, H_, H_, gxH);
    packW_k<<<gpH, blk, 0, stream>>>(Wv, WPa, H_);
    gemm_i8t<2><<<nwgH, blk, 0, stream>>>(HQ8, WPa, sv, bv, nullptr, nullptr, Vbf, H_, H_, gxH);

    rope_k<<<R_, blk, 0, stream>>>(Qb, Kb, Kbf);
    attn_mfma_k<<<B_ * NH_ * (S_ / 64), blk, 0, stream>>>(Qb, Kbf, Vbf, HQ8, o_sc);

    packW_k<<<gpH, blk, 0, stream>>>(Wo, WPb, H_);
    gemm_i8t<0><<<nwgH, blk, 0, stream>>>(HQ8, WPb, so, bo, hidden, Hb, nullptr, H_, H_, gxH);

    rmsnorm_quant_k<<<R_, blk, 0, stream>>>(Hb, ln2, HQ8);

    packW_k<<<gpI, blk, 0, stream>>>(Wg, WPa, H_);
    packW_k<<<gpI, blk, 0, stream>>>(Wu, WPu, H_);
    gemm_gu<<<nwgI, blk, 0, stream>>>(HQ8, WPa, WPu, sg, bg, su, bu,
                                      d_sc, AQ8, I_, H_, gxH);
    packW_k<<<gpD, blk, 0, stream>>>(Wd, WPd, I_);
    gemm_i8t<0><<<nwgH, blk, 0, stream>>>(AQ8, WPd, sd, bd, Hb, out, nullptr, H_, I_, gxH);
}

// Round 17
// 917.425 us; speedup vs baseline: 1.0762x; 1.0139x over previous
//
#include <hip/hip_runtime.h>
#include <math.h>

#define B_  2
#define S_  1024
#define H_  4096
#define NH_ 32
#define HD_ 128
#define I_  11008
#define R_  2048   // B*S tokens

typedef __attribute__((ext_vector_type(4))) int i32x4;
typedef __attribute__((ext_vector_type(4))) float f32x4;
typedef __attribute__((ext_vector_type(8))) short bf16x8;

// Tiled int8 layout (v1, validated): for matrix [Rows][K], nk = K/64;
// tile (rb, kt) is 8192 B at ((rb*nk + kt)<<13), internally
// [kgrp 0..3][row 0..127][16B]  (kgrp = (k%64)/16).
//
// r14 LESSON: kernels with hand-counted s_waitcnt vmcnt(N) must never spill —
// scratch buffer ops count toward vmcnt. Keep launch_bounds at the no-spill
// occupancy ((256,2) for the dual-acc GEMMs; 3-acc QKV would spill — don't).
// r7 LESSON: global_load_lds global src is PER-LANE; LDS dest is wave-uniform.

// ---------------------------------------------------------------------------
__device__ __forceinline__ void gload_lds16(const void* g, void* l) {
    __builtin_amdgcn_global_load_lds(
        (const __attribute__((address_space(1))) unsigned int*)g,
        (__attribute__((address_space(3))) unsigned int*)l, 16, 0, 0);
}

__device__ __forceinline__ unsigned short f2bf(float f) {
    unsigned int u = __float_as_uint(f);
    u += 0x7fffu + ((u >> 16) & 1u);   // RNE
    return (unsigned short)(u >> 16);
}

// ---------------------------------------------------------------------------
// Pack one W (int32 [N][K]) into tiled-i8. Grid: (K/64, N/128).
__global__ __launch_bounds__(256)
void packW_k(const int* __restrict__ W, signed char* __restrict__ out, const int K)
{
    const int kt = blockIdx.x, cb = blockIdx.y, nk = gridDim.x;
    const int t = threadIdx.x;
    int* otile = (int*)(out + ((long)(cb * nk + kt) << 13));
#pragma unroll
    for (int i = 0; i < 8; ++i) {
        const int o = i * 256 + t;                 // int32 index in tile
        const int g = o >> 9, r = (o >> 2) & 127, jj = o & 3;
        const int4 w4 = *(const int4*)(W + (long)(cb * 128 + r) * K + kt * 64 + g * 16 + jj * 4);
        otile[o] = (w4.x & 255) | ((w4.y & 255) << 8) | ((w4.z & 255) << 16) | (w4.w << 24);
    }
}

// ---------------------------------------------------------------------------
// RMSNorm + int8 quant (scale folded into w). Output in tiled-i8 (nk=64).
__global__ __launch_bounds__(256)
void rmsnorm_quant_k(const float* __restrict__ x, const float* __restrict__ w,
                     signed char* __restrict__ out)
{
    __shared__ float red[4];
    const int tid = threadIdx.x;
    const long row = blockIdx.x;
    const float4* xr = (const float4*)(x + row * H_);
    float4 xv[4];
    float ss = 0.f;
#pragma unroll
    for (int i = 0; i < 4; ++i) {
        xv[i] = xr[tid + i * 256];
        ss += xv[i].x * xv[i].x + xv[i].y * xv[i].y
            + xv[i].z * xv[i].z + xv[i].w * xv[i].w;
    }
#pragma unroll
    for (int off = 32; off; off >>= 1) ss += __shfl_xor(ss, off);
    if ((tid & 63) == 0) red[tid >> 6] = ss;
    __syncthreads();
    const float tot = red[0] + red[1] + red[2] + red[3];
    const float sc = 1.f / sqrtf(tot * (1.f / (float)H_) + 1e-6f);
    const float4* wr = (const float4*)w;
    int* ob = (int*)out;
    const long rb = row >> 7;
    const int rr = (int)(row & 127);
#pragma unroll
    for (int i = 0; i < 4; ++i) {
        const float4 wv = wr[tid + i * 256];
        const int b0 = (int)fminf(fmaxf(rintf(xv[i].x * sc * wv.x), -128.f), 127.f);
        const int b1 = (int)fminf(fmaxf(rintf(xv[i].y * sc * wv.y), -128.f), 127.f);
        const int b2 = (int)fminf(fmaxf(rintf(xv[i].z * sc * wv.z), -128.f), 127.f);
        const int b3 = (int)fminf(fmaxf(rintf(xv[i].w * sc * wv.w), -128.f), 127.f);
        const int packed = (b0 & 255) | ((b1 & 255) << 8) | ((b2 & 255) << 16) | (b3 << 24);
        const int j4 = tid + i * 256;              // int32 group within row
        const long a32 = ((rb * 64 + (j4 >> 4)) << 11) + (((j4 >> 2) & 3) << 9)
                       + (rr << 2) + (j4 & 3);
        ob[a32] = packed;
    }
}

// ---------------------------------------------------------------------------
// int8 GEMM (round-8 validated): BK=128 double-step, depth-2 ring, counted
// vmcnt(8), 64KB LDS -> 2 blocks/CU. Wave-out 64x64 (acc[4][4]).
__global__ __launch_bounds__(256, 2)
void gemm_i8t(const signed char* __restrict__ A8, const signed char* __restrict__ W8,
              const float* __restrict__ scale_ptr, const float* __restrict__ bias,
              const float* __restrict__ residual, float* __restrict__ C,
              const int N, const int K, const int gx)
{
    __shared__ __align__(16) signed char lsA[2][16384];
    __shared__ __align__(16) signed char lsB[2][16384];

    int bid = blockIdx.x;
    {   // bijective XCD chunked remap (m204)
        const int nwg = gridDim.x;
        const int q = nwg >> 3, r = nwg & 7;
        const int xcd = bid & 7, idx = bid >> 3;
        bid = (xcd < r) ? (xcd * (q + 1) + idx)
                        : (r * (q + 1) + (xcd - r) * q + idx);
    }
    const int bx = bid % gx, by = bid / gx;

    const int tid  = threadIdx.x;
    const int lane = tid & 63, wid = tid >> 6;
    const int bm = bx << 7, bn = by << 7;
    const int wm = (wid >> 1) << 6, wn = (wid & 1) << 6;

    i32x4 acc[4][4];
#pragma unroll
    for (int m = 0; m < 4; ++m)
#pragma unroll
        for (int n = 0; n < 4; ++n) acc[m][n] = (i32x4){0, 0, 0, 0};

    const int nk  = K >> 6;
    const int nk2 = K >> 7;
    const signed char* abase = A8 + ((long)bx * nk << 13);
    const signed char* bbase = W8 + ((long)by * nk << 13);
    const int sgg = wid * 4096 + lane * 16;        // GLOBAL src: per-lane
    const int sgl = wid * 4096;                    // LDS dest: wave-uniform

#pragma unroll
    for (int c = 0; c < 4; ++c) {
        gload_lds16(abase + sgg + c * 1024, lsA[0] + sgl + c * 1024);
        gload_lds16(bbase + sgg + c * 1024, lsB[0] + sgl + c * 1024);
    }

    for (int kt = 0; kt < nk2; ++kt) {
        const int cur = kt & 1, nxt = cur ^ 1;
        if (kt + 1 < nk2) {
            const signed char* at = abase + ((long)(kt + 1) << 14);
            const signed char* bt = bbase + ((long)(kt + 1) << 14);
#pragma unroll
            for (int c = 0; c < 4; ++c) {
                gload_lds16(at + sgg + c * 1024, lsA[nxt] + sgl + c * 1024);
                gload_lds16(bt + sgg + c * 1024, lsB[nxt] + sgl + c * 1024);
            }
            asm volatile("s_waitcnt vmcnt(8)" ::: "memory");
        } else {
            asm volatile("s_waitcnt vmcnt(0)" ::: "memory");
        }
        __builtin_amdgcn_s_barrier();

        const int kg = (lane >> 4) * 2048, fr = (lane & 15) * 16;
#pragma unroll
        for (int s = 0; s < 2; ++s) {
            const int off = s * 8192;
            i32x4 af[4], bf[4];
#pragma unroll
            for (int m = 0; m < 4; ++m)
                af[m] = *(const i32x4*)(lsA[cur] + off + kg + wm * 16 + m * 256 + fr);
#pragma unroll
            for (int n = 0; n < 4; ++n)
                bf[n] = *(const i32x4*)(lsB[cur] + off + kg + wn * 16 + n * 256 + fr);
            __builtin_amdgcn_s_setprio(1);
#pragma unroll
            for (int m = 0; m < 4; ++m)
#pragma unroll
                for (int n = 0; n < 4; ++n)
                    acc[m][n] = __builtin_amdgcn_mfma_i32_16x16x64_i8(af[m], bf[n], acc[m][n], 0, 0, 0);
            __builtin_amdgcn_s_setprio(0);
        }
        __builtin_amdgcn_s_barrier();
    }

    const float s = *scale_ptr;
    const int rq = (lane >> 4) * 4, fc = lane & 15;
#pragma unroll
    for (int m = 0; m < 4; ++m) {
#pragma unroll
        for (int n = 0; n < 4; ++n) {
            const int col = bn + wn + n * 16 + fc;
            const float bcol = bias[col];
#pragma unroll
            for (int r = 0; r < 4; ++r) {
                const int row = bm + wm + m * 16 + rq + r;
                float v = (float)acc[m][n][r] * s + bcol;
                if (residual) v += residual[(long)row * N + col];
                C[(long)row * N + col] = v;
            }
        }
    }
}

// ---------------------------------------------------------------------------
// Dual-accumulator shared-A GEMM skeleton (gemm_gu pattern, r11 validated):
// one block stages A once and computes two 128x128 output tiles from two
// weight operands. 48KB LDS ring, counted vmcnt(6), (256,2) no-spill.
// EPI 0 (gemm_gu): silu(g)*u -> quant -> AQ8 tiled-i8.
// EPI 1 (gemm_kv): K fp32 (pre-rope) + V bf16.
template<int EPI>
__global__ __launch_bounds__(256, 2)
void gemm_dual(const signed char* __restrict__ A8, const signed char* __restrict__ G8,
               const signed char* __restrict__ U8,
               const float* __restrict__ s1_p, const float* __restrict__ b1,
               const float* __restrict__ s2_p, const float* __restrict__ b2,
               const float* __restrict__ qscale, signed char* __restrict__ out8,
               float* __restrict__ Cf, unsigned short* __restrict__ Cbf,
               const int N, const int K, const int gx)
{
    __shared__ __align__(16) signed char lsA[2][8192];
    __shared__ __align__(16) signed char lsG[2][8192];
    __shared__ __align__(16) signed char lsU[2][8192];

    int bid = blockIdx.x;
    {   // bijective XCD chunked remap
        const int nwg = gridDim.x;
        const int q = nwg >> 3, r = nwg & 7;
        const int xcd = bid & 7, idx = bid >> 3;
        bid = (xcd < r) ? (xcd * (q + 1) + idx)
                        : (r * (q + 1) + (xcd - r) * q + idx);
    }
    const int bx = bid % gx, by = bid / gx;
    const int tid = threadIdx.x, lane = tid & 63, wid = tid >> 6;
    const int bm = bx << 7, bn = by << 7;
    const int wm = (wid >> 1) << 6, wn = (wid & 1) << 6;

    i32x4 ag[4][4], au[4][4];
#pragma unroll
    for (int m = 0; m < 4; ++m)
#pragma unroll
        for (int n = 0; n < 4; ++n) {
            ag[m][n] = (i32x4){0, 0, 0, 0};
            au[m][n] = (i32x4){0, 0, 0, 0};
        }

    const int nk = K >> 6;
    const signed char* abase = A8 + ((long)bx * nk << 13);
    const signed char* gbase = G8 + ((long)by * nk << 13);
    const signed char* ubase = U8 + ((long)by * nk << 13);
    const int sgg = wid * 2048 + lane * 16;        // GLOBAL src: per-lane
    const int sgl = wid * 2048;                    // LDS dest: wave-uniform

#pragma unroll
    for (int c = 0; c < 2; ++c) {
        gload_lds16(abase + sgg + c * 1024, lsA[0] + sgl + c * 1024);
        gload_lds16(gbase + sgg + c * 1024, lsG[0] + sgl + c * 1024);
        gload_lds16(ubase + sgg + c * 1024, lsU[0] + sgl + c * 1024);
    }

    for (int kt = 0; kt < nk; ++kt) {
        const int cur = kt & 1, nxt = cur ^ 1;
        if (kt + 1 < nk) {
            const signed char* at = abase + ((long)(kt + 1) << 13);
            const signed char* gt = gbase + ((long)(kt + 1) << 13);
            const signed char* ut = ubase + ((long)(kt + 1) << 13);
#pragma unroll
            for (int c = 0; c < 2; ++c) {
                gload_lds16(at + sgg + c * 1024, lsA[nxt] + sgl + c * 1024);
                gload_lds16(gt + sgg + c * 1024, lsG[nxt] + sgl + c * 1024);
                gload_lds16(ut + sgg + c * 1024, lsU[nxt] + sgl + c * 1024);
            }
            asm volatile("s_waitcnt vmcnt(6)" ::: "memory");   // drain step kt's 6
        } else {
            asm volatile("s_waitcnt vmcnt(0)" ::: "memory");
        }
        __builtin_amdgcn_s_barrier();              // step kt visible

        const int kg = (lane >> 4) * 2048, fr = (lane & 15) * 16;
        i32x4 af[4], gf[4], uf[4];
#pragma unroll
        for (int m = 0; m < 4; ++m)
            af[m] = *(const i32x4*)(lsA[cur] + kg + wm * 16 + m * 256 + fr);
#pragma unroll
        for (int n = 0; n < 4; ++n) {
            gf[n] = *(const i32x4*)(lsG[cur] + kg + wn * 16 + n * 256 + fr);
            uf[n] = *(const i32x4*)(lsU[cur] + kg + wn * 16 + n * 256 + fr);
        }
        __builtin_amdgcn_s_setprio(1);
#pragma unroll
        for (int m = 0; m < 4; ++m)
#pragma unroll
            for (int n = 0; n < 4; ++n) {
                ag[m][n] = __builtin_amdgcn_mfma_i32_16x16x64_i8(af[m], gf[n], ag[m][n], 0, 0, 0);
                au[m][n] = __builtin_amdgcn_mfma_i32_16x16x64_i8(af[m], uf[n], au[m][n], 0, 0, 0);
            }
        __builtin_amdgcn_s_setprio(0);
        __builtin_amdgcn_s_barrier();              // buf[cur] free
    }

    const float s1 = *s1_p, s2 = *s2_p;
    const int rq = (lane >> 4) * 4, fc = lane & 15;
    if (EPI == 0) {
        const float dinv = 1.f / qscale[0];
        const int nko = N >> 6;
#pragma unroll
        for (int m = 0; m < 4; ++m) {
#pragma unroll
            for (int n = 0; n < 4; ++n) {
                const int col = bn + wn + n * 16 + fc;
                const float bgc = b1[col], buc = b2[col];
                const int ktc = col >> 6, kgc = (col >> 4) & 3, jc = col & 15;
#pragma unroll
                for (int r = 0; r < 4; ++r) {
                    const int row = bm + wm + m * 16 + rq + r;
                    const float g = (float)ag[m][n][r] * s1 + bgc;
                    const float u = (float)au[m][n][r] * s2 + buc;
                    const float a = g / (1.f + __expf(-g)) * u;
                    const float qv = fminf(fmaxf(rintf(a * dinv), -128.f), 127.f);
                    const long addr = (((long)(row >> 7) * nko + ktc) << 13)
                                    + (kgc << 11) + ((row & 127) << 4) + jc;
                    out8[addr] = (signed char)(int)qv;
                }
            }
        }
    } else {
        // EPI 1: G-side -> K fp32 (rope consumes fp32), U-side -> V bf16
#pragma unroll
        for (int m = 0; m < 4; ++m) {
#pragma unroll
            for (int n = 0; n < 4; ++n) {
                const int col = bn + wn + n * 16 + fc;
                const float bkc = b1[col], bvc = b2[col];
#pragma unroll
                for (int r = 0; r < 4; ++r) {
                    const int row = bm + wm + m * 16 + rq + r;
                    Cf[(long)row * N + col]  = (float)ag[m][n][r] * s1 + bkc;
                    Cbf[(long)row * N + col] = f2bf((float)au[m][n][r] * s2 + bvc);
                }
            }
        }
    }
}

// ---------------------------------------------------------------------------
// RoPE: Q in-place fp32; K read fp32 -> roped -> written bf16.
__global__ __launch_bounds__(256)
void rope_k(float* __restrict__ q, const float* __restrict__ kin,
            unsigned short* __restrict__ kbf)
{
    const int row = blockIdx.x;            // token index b*S+s
    const int s = row & (S_ - 1);
    float* qr = q + (long)row * H_;
    const float* kr = kin + (long)row * H_;
    unsigned short* ko = kbf + (long)row * H_;
    for (int t = threadIdx.x; t < NH_ * 64; t += 256) {
        const int nh = t >> 6, i = t & 63;
        const float inv = powf(10000.f, -(float)(2 * i) * (1.f / 128.f));
        const float f = (float)s * inv;
        float sn, c;
        sincosf(f, &sn, &c);
        const int base = nh * 128 + i;
        const float q0 = qr[base], q1 = qr[base + 64];
        qr[base]      = q0 * c - q1 * sn;
        qr[base + 64] = q1 * c + q0 * sn;
        const float k0 = kr[base], k1 = kr[base + 64];
        ko[base]      = f2bf(k0 * c - k1 * sn);
        ko[base + 64] = f2bf(k1 * c + k0 * sn);
    }
}

// ---------------------------------------------------------------------------
// Flash attention, bf16 MFMA; K/V arrive pre-converted bf16.
__global__ __launch_bounds__(256, 3)
void attn_mfma_k(const float* __restrict__ q, const unsigned short* __restrict__ kbf,
                 const unsigned short* __restrict__ vbf, signed char* __restrict__ out8,
                 const float* __restrict__ osc)
{
    __shared__ __align__(16) char lsK[8192];        // [32 krow][128 d] bf16, XOR swizzle
    __shared__ __align__(16) char lsV[10240];       // V^T [128 d][40 pitch] bf16
    __shared__ __align__(16) char lsP[4][1024];     // per-wave P [16][32] bf16, XOR swizzle

    const int tid = threadIdx.x, lane = tid & 63, wid = tid >> 6;
    const int bid = blockIdx.x;
    const int qt = 15 - (bid >> 6);                 // reversed: long blocks first
    const int bh = bid & 63;
    const int b = bh >> 5, h = bh & 31;
    const int q0 = qt * 64;
    const int qw = q0 + wid * 16;                   // this wave's first q row

    const float* qbase = q + (long)(b * S_) * H_ + (long)h * HD_;
    const unsigned short* kbase = kbf + (long)(b * S_) * H_ + (long)h * HD_;
    const unsigned short* vbase = vbf + (long)(b * S_) * H_ + (long)h * HD_;

    const int frow = lane & 15, fgrp = lane >> 4;
    const float sc = 0.08838834764831845f;          // 1/sqrt(128), folded into Q

    bf16x8 qf[4];
    {
        const float* qr = qbase + (long)(qw + frow) * H_;
#pragma unroll
        for (int c = 0; c < 4; ++c) {
            const float4 a = *(const float4*)(qr + c * 32 + fgrp * 8);
            const float4 bq = *(const float4*)(qr + c * 32 + fgrp * 8 + 4);
            bf16x8 t;
            t[0] = (short)f2bf(a.x * sc);  t[1] = (short)f2bf(a.y * sc);
            t[2] = (short)f2bf(a.z * sc);  t[3] = (short)f2bf(a.w * sc);
            t[4] = (short)f2bf(bq.x * sc); t[5] = (short)f2bf(bq.y * sc);
            t[6] = (short)f2bf(bq.z * sc); t[7] = (short)f2bf(bq.w * sc);
            qf[c] = t;
        }
    }

    f32x4 oacc[8];
#pragma unroll
    for (int n2 = 0; n2 < 8; ++n2) oacc[n2] = (f32x4){0.f, 0.f, 0.f, 0.f};
    float mr[4] = {-1e30f, -1e30f, -1e30f, -1e30f};
    float lr[4] = {0.f, 0.f, 0.f, 0.f};

    const int nt = (q0 >> 5) + 2;
    for (int kt = 0; kt < nt; ++kt) {
        if (kt) __syncthreads();
        {
            const unsigned short* kg = kbase + (long)(kt * 32) * H_;
            const unsigned short* vg = vbase + (long)(kt * 32) * H_;
#pragma unroll
            for (int i = 0; i < 2; ++i) {
                const int lin = i * 256 + tid;      // 512 units of 8 bf16
                const int kr = lin >> 4;            // 0..31
                const int d8 = (lin & 15) * 8;      // 0..120
                const bf16x8 kv = *(const bf16x8*)(kg + (long)kr * H_ + d8);
                *(bf16x8*)(lsK + kr * 256 + ((d8 * 2) ^ ((kr & 7) << 4))) = kv;
                const bf16x8 vv = *(const bf16x8*)(vg + (long)kr * H_ + d8);
#pragma unroll
                for (int e = 0; e < 8; ++e)
                    *(unsigned short*)(lsV + (d8 + e) * 80 + kr * 2) = (unsigned short)vv[e];
            }
        }
        __syncthreads();

        if (kt * 32 <= qw + 15) {
            f32x4 s0 = (f32x4){0.f, 0.f, 0.f, 0.f};
            f32x4 s1 = (f32x4){0.f, 0.f, 0.f, 0.f};
            const int swz = (frow & 7) << 4;
#pragma unroll
            for (int c = 0; c < 4; ++c) {
                const int dby = c * 64 + fgrp * 16;
                const bf16x8 kfA = *(const bf16x8*)(lsK + frow * 256 + (dby ^ swz));
                const bf16x8 kfB = *(const bf16x8*)(lsK + (frow + 16) * 256 + (dby ^ swz));
                s0 = __builtin_amdgcn_mfma_f32_16x16x32_bf16(qf[c], kfA, s0, 0, 0, 0);
                s1 = __builtin_amdgcn_mfma_f32_16x16x32_bf16(qf[c], kfB, s1, 0, 0, 0);
            }

            const int colg0 = kt * 32 + frow;
            float cf[4];
#pragma unroll
            for (int r = 0; r < 4; ++r) {
                const int rowg = qw + fgrp * 4 + r;
                const float a0 = (colg0 <= rowg) ? s0[r] : -1e30f;
                const float a1 = (colg0 + 16 <= rowg) ? s1[r] : -1e30f;
                float mx = fmaxf(a0, a1);
#pragma unroll
                for (int off2 = 1; off2 < 16; off2 <<= 1) mx = fmaxf(mx, __shfl_xor(mx, off2));
                const float mnew = fmaxf(mr[r], mx);
                cf[r] = __expf(mr[r] - mnew);
                mr[r] = mnew;
                const float p0 = __expf(a0 - mnew);
                const float p1 = __expf(a1 - mnew);
                float sm = p0 + p1;
#pragma unroll
                for (int off2 = 1; off2 < 16; off2 <<= 1) sm += __shfl_xor(sm, off2);
                lr[r] = lr[r] * cf[r] + sm;
                const int row = fgrp * 4 + r;
                const int psw = (row & 3) << 4;
                *(unsigned short*)(lsP[wid] + row * 64 + ((frow * 2) ^ psw)) = f2bf(p0);
                *(unsigned short*)(lsP[wid] + row * 64 + (((16 + frow) * 2) ^ psw)) = f2bf(p1);
            }
#pragma unroll
            for (int n2 = 0; n2 < 8; ++n2) {
#pragma unroll
                for (int r = 0; r < 4; ++r) oacc[n2][r] *= cf[r];
            }
            const bf16x8 pf = *(const bf16x8*)(lsP[wid] + frow * 64 + ((fgrp * 16) ^ ((frow & 3) << 4)));
#pragma unroll
            for (int n2 = 0; n2 < 8; ++n2) {
                const bf16x8 vf = *(const bf16x8*)(lsV + (n2 * 16 + frow) * 80 + fgrp * 16);
                oacc[n2] = __builtin_amdgcn_mfma_f32_16x16x32_bf16(pf, vf, oacc[n2], 0, 0, 0);
            }
        }
    }

    // epilogue: o = oacc/l, q8 = clip(rint(o/osc)) -> tiled-i8 (nk = 64)
    const float oinv = 1.f / osc[0];
    float inv[4];
#pragma unroll
    for (int r = 0; r < 4; ++r) inv[r] = 1.f / lr[r];
#pragma unroll
    for (int n2 = 0; n2 < 8; ++n2) {
        const int kk = h * 128 + n2 * 16 + frow;
        const int ktc = kk >> 6, kgc = (kk >> 4) & 3, jc = kk & 15;
#pragma unroll
        for (int r = 0; r < 4; ++r) {
            const int rowt = b * S_ + qw + fgrp * 4 + r;
            const float ov = oacc[n2][r] * inv[r];
            const float qv = fminf(fmaxf(rintf(ov * oinv), -128.f), 127.f);
            const long addr = (((long)(rowt >> 7) * 64 + ktc) << 13)
                            + (kgc << 11) + ((rowt & 127) << 4) + jc;
            out8[addr] = (signed char)(int)qv;
        }
    }
}

// ---------------------------------------------------------------------------
extern "C" void kernel_launch(void* const* d_in, const int* in_sizes, int n_in,
                              void* d_out, int out_size, void* d_ws, size_t ws_size,
                              hipStream_t stream)
{
    const float* hidden = (const float*)d_in[0];
    const float* ln1 = (const float*)d_in[1];
    const float* ln2 = (const float*)d_in[2];
    const int* Wq = (const int*)d_in[3];
    const int* Wk = (const int*)d_in[4];
    const int* Wv = (const int*)d_in[5];
    const int* Wo = (const int*)d_in[6];
    const int* Wg = (const int*)d_in[7];
    const int* Wu = (const int*)d_in[8];
    const int* Wd = (const int*)d_in[9];
    const float* bq = (const float*)d_in[10];
    const float* bk = (const float*)d_in[11];
    const float* bv = (const float*)d_in[12];
    const float* bo = (const float*)d_in[13];
    const float* bg = (const float*)d_in[14];
    const float* bu = (const float*)d_in[15];
    const float* bd = (const float*)d_in[16];
    const float* sq = (const float*)d_in[17];
    const float* sk = (const float*)d_in[18];
    const float* sv = (const float*)d_in[19];
    const float* so = (const float*)d_in[20];
    const float* sg = (const float*)d_in[21];
    const float* su = (const float*)d_in[22];
    const float* sd = (const float*)d_in[23];
    const float* o_sc = (const float*)d_in[24];
    const float* d_sc = (const float*)d_in[25];

    // workspace layout (MiB offsets, peak 229 MiB):
    //  [0,8)     HQ8 tiled i8 (hq / oq / hq2, sequential reuse)
    //  [8,30)    AQ8 tiled i8 (2048 x 11008)
    //  [30,74)   WPa: Wq -> Wv -> Wg packed (44 MiB)
    //  [74,106)  Qb fp32 -> (post-attn) Hb
    //  [106,138) Kb fp32 (dead after rope)
    //  [138,154) Vbf bf16 ; [154,170) Kbf bf16   (dead after attn)
    //  [170,186) WPb: Wk -> Wo packed (16 MiB)
    //  [186,229) WPu: Wu packed (43 MiB)
    //  [106,149) WPd: Wd packed (43 MiB, over dead Kb/Vbf, packed after attn)
    char* ws = (char*)d_ws;
    signed char* HQ8 = (signed char*)ws;
    signed char* AQ8 = (signed char*)(ws + ((size_t)8 << 20));
    signed char* WPa = (signed char*)(ws + ((size_t)30 << 20));
    float* Qb = (float*)(ws + ((size_t)74 << 20));
    float* Kb = (float*)(ws + ((size_t)106 << 20));
    unsigned short* Vbf = (unsigned short*)(ws + ((size_t)138 << 20));
    unsigned short* Kbf = (unsigned short*)(ws + ((size_t)154 << 20));
    signed char* WPb = (signed char*)(ws + ((size_t)170 << 20));
    signed char* WPu = (signed char*)(ws + ((size_t)186 << 20));
    signed char* WPd = (signed char*)(ws + ((size_t)106 << 20));
    float* Hb = Qb;
    float* out = (float*)d_out;

    const dim3 blk(256);
    const int gxH = R_ / 128;                 // 16 row blocks
    const int nwgH = gxH * (H_ / 128);        // 512
    const int nwgI = gxH * (I_ / 128);        // 1376
    const dim3 gpH(H_ / 64, H_ / 128);        // pack grids: (nk, N/128)
    const dim3 gpI(H_ / 64, I_ / 128);
    const dim3 gpD(I_ / 64, H_ / 128);

    rmsnorm_quant_k<<<R_, blk, 0, stream>>>(hidden, ln1, HQ8);

    packW_k<<<gpH, blk, 0, stream>>>(Wq, WPa, H_);
    gemm_i8t<<<nwgH, blk, 0, stream>>>(HQ8, WPa, sq, bq, nullptr, Qb, H_, H_, gxH);
    packW_k<<<gpH, blk, 0, stream>>>(Wk, WPb, H_);
    packW_k<<<gpH, blk, 0, stream>>>(Wv, WPa, H_);
    // fused K+V projection: K fp32 -> Kb, V bf16 -> Vbf (shared-A dual GEMM)
    gemm_dual<1><<<nwgH, blk, 0, stream>>>(HQ8, WPb, WPa, sk, bk, sv, bv,
                                           nullptr, nullptr, Kb, Vbf, H_, H_, gxH);

    rope_k<<<R_, blk, 0, stream>>>(Qb, Kb, Kbf);
    attn_mfma_k<<<B_ * NH_ * (S_ / 64), blk, 0, stream>>>(Qb, Kbf, Vbf, HQ8, o_sc);

    packW_k<<<gpH, blk, 0, stream>>>(Wo, WPb, H_);
    gemm_i8t<<<nwgH, blk, 0, stream>>>(HQ8, WPb, so, bo, hidden, Hb, H_, H_, gxH);

    rmsnorm_quant_k<<<R_, blk, 0, stream>>>(Hb, ln2, HQ8);

    packW_k<<<gpI, blk, 0, stream>>>(Wg, WPa, H_);
    packW_k<<<gpI, blk, 0, stream>>>(Wu, WPu, H_);
    gemm_dual<0><<<nwgI, blk, 0, stream>>>(HQ8, WPa, WPu, sg, bg, su, bu,
                                           d_sc, AQ8, nullptr, nullptr, I_, H_, gxH);
    packW_k<<<gpD, blk, 0, stream>>>(Wd, WPd, I_);
    gemm_i8t<<<nwgH, blk, 0, stream>>>(AQ8, WPd, sd, bd, Hb, out, H_, I_, gxH);
}